// Round 14
// baseline (749.161 us; speedup 1.0000x reference)
//
#include <hip/hip_runtime.h>
#include <hip/hip_cooperative_groups.h>
#include <cstdint>
#include <cstddef>

namespace cg = cooperative_groups;

#define Bb 2
#define Ss 1024
#define Dd 768
#define Hh 8
#define HDh 96
#define Mm 3072
#define Vv 32000
#define KVr 2049   // 2S+1

typedef __attribute__((ext_vector_type(8))) short short8v;
typedef __attribute__((ext_vector_type(4))) short short4v;
typedef __attribute__((ext_vector_type(4))) float f32x4;

#define GL16(gp, lp) __builtin_amdgcn_global_load_lds( \
    (const __attribute__((address_space(1))) void*)(gp), \
    (__attribute__((address_space(3))) void*)(lp), 16, 0, 0)

static __device__ __forceinline__ short f2bf(float f) {
  union { float f; unsigned u; } x; x.f = f;
  unsigned r = (x.u + 0x7FFFu + ((x.u >> 16) & 1u)) >> 16;  // RNE
  return (short)(r & 0xFFFFu);
}

static __device__ __forceinline__ float bf2f(short s) {
  union { unsigned u; float f; } x; x.u = ((unsigned)(unsigned short)s) << 16;
  return x.f;
}

static __device__ __forceinline__ float gelu_f(float v) {
  float u = 0.7978845608028654f * (v + 0.044715f * v * v * v);
  float au = fabsf(u);
  float e = __expf(2.f * au);
  float t = 1.f - 2.f / (e + 1.f);     // tanh(|u|), safe at inf
  return 0.5f * v * (1.f + copysignf(t, u));
}

static __device__ __forceinline__ float blk_sum(float val, float* sh) {
  #pragma unroll
  for (int off = 32; off >= 1; off >>= 1) val += __shfl_xor(val, off);
  __syncthreads();
  if ((threadIdx.x & 63) == 0) sh[threadIdx.x >> 6] = val;
  __syncthreads();
  return sh[0] + sh[1] + sh[2] + sh[3];
}

// ---------------- cooperative t-path: thin1 -> thin1p -> film1p -> film2 ----------------
__global__ __launch_bounds__(256) void tpath_coop(
    const float* __restrict__ temb,
    const float* __restrict__ tm_w1, const float* __restrict__ tm_b1,
    const float* __restrict__ tm_w2, const float* __restrict__ tm_b2,
    const float* __restrict__ film_w, const float* __restrict__ film_b,
    float* __restrict__ part2a, float* __restrict__ part2b, float* __restrict__ part2c,
    float* __restrict__ f0, float* __restrict__ f1)
{
  cg::grid_group grid = cg::this_grid();
  __shared__ float a0s[48], a1s[48];
  const int tid = threadIdx.x;
  const int nb = blockIdx.x % 12, ks = blockIdx.x / 12;
  const int n = nb * 256 + tid;

  // stage 1: t1 = temb @ tm_w1 partials (K=768, 64 splits, kl=12)
  {
    const int kbeg = ks * 12;
    for (int k = tid; k < 12; k += 256) { a0s[k] = temb[kbeg + k]; a1s[k] = temb[768 + kbeg + k]; }
    __syncthreads();
    float acc0 = 0.f, acc1 = 0.f;
    for (int k = 0; k < 12; ++k) {
      float w = tm_w1[(size_t)(kbeg + k) * 3072 + n];
      acc0 = fmaf(a0s[k], w, acc0);
      acc1 = fmaf(a1s[k], w, acc1);
    }
    part2a[(size_t)ks * 6144 + n] = acc0;
    part2a[(size_t)ks * 6144 + 3072 + n] = acc1;
  }
  grid.sync();

  // stage 2: tb = gelu(t1+b1) @ tm_w2 partials (K=3072, 64 splits, kl=48)
  {
    const int kbeg = ks * 48;
    for (int j = tid; j < 96; j += 256) {
      int row = j / 48, k = j % 48;
      float v = tm_b1[kbeg + k];
      for (int s = 0; s < 64; ++s) v += part2a[(size_t)s * 6144 + (size_t)row * 3072 + kbeg + k];
      v = gelu_f(v);
      if (row) a1s[k] = v; else a0s[k] = v;
    }
    __syncthreads();
    float acc0 = 0.f, acc1 = 0.f;
    for (int k = 0; k < 48; ++k) {
      float w = tm_w2[(size_t)(kbeg + k) * 3072 + n];
      acc0 = fmaf(a0s[k], w, acc0);
      acc1 = fmaf(a1s[k], w, acc1);
    }
    part2b[(size_t)ks * 6144 + n] = acc0;
    part2b[(size_t)ks * 6144 + 3072 + n] = acc1;
  }
  grid.sync();

  // stage 3: film = (tb+tm_b2) @ film_w partials
  {
    const int kbeg = ks * 48;
    for (int j = tid; j < 96; j += 256) {
      int row = j / 48, k = j % 48;
      float v = tm_b2[kbeg + k];
      for (int s = 0; s < 64; ++s) v += part2b[(size_t)s * 6144 + (size_t)row * 3072 + kbeg + k];
      if (row) a1s[k] = v; else a0s[k] = v;
    }
    __syncthreads();
    const int col = (n >= 1536) ? (n - 1536) : n;
    const float* Wp = film_w + ((n < 1536) ? (size_t)0 : (size_t)3072 * 1536)
                             + (size_t)kbeg * 1536 + col;
    float acc0 = 0.f, acc1 = 0.f;
    for (int k = 0; k < 48; ++k) {
      float w = Wp[(size_t)k * 1536];
      acc0 = fmaf(a0s[k], w, acc0);
      acc1 = fmaf(a1s[k], w, acc1);
    }
    part2c[(size_t)ks * 6144 + n] = acc0;
    part2c[(size_t)ks * 6144 + 3072 + n] = acc1;
  }
  grid.sync();

  // stage 4: film2 reduction (12 blocks)
  if (blockIdx.x < 12) {
    const int nn = blockIdx.x * 256 + tid;
    float a0 = film_b[nn], a1 = a0;
    for (int s = 0; s < 64; ++s) {
      a0 += part2c[(size_t)s * 6144 + nn];
      a1 += part2c[(size_t)s * 6144 + 3072 + nn];
    }
    float* dst = (nn < 1536) ? f0 : f1;
    const int c = (nn >= 1536) ? (nn - 1536) : nn;
    dst[c] = a0;
    dst[1536 + c] = a1;
  }
}

// ---------------- prep (0-2049) + QKVO convert / bias (2050-2626) ----------------
__global__ __launch_bounds__(256) void prep_conv(
    const float* __restrict__ l2r, const float* __restrict__ r2l,
    const float* __restrict__ temb,
    const float* __restrict__ s1, const float* __restrict__ b1,
    const float* __restrict__ s2, const float* __restrict__ b2,
    float* __restrict__ inputs, short* __restrict__ all_e,
    const float* __restrict__ W0, const float* __restrict__ W1,
    const float* __restrict__ W2, const float* __restrict__ W3,
    const float* __restrict__ bk, const float* __restrict__ bv,
    short* __restrict__ Wt, float* __restrict__ kvb)
{
  __shared__ float sh[4];
  __shared__ short T[64][72];
  const int tid = threadIdx.x;

  if (blockIdx.x >= 2050) {
    const int cb = blockIdx.x - 2050;   // 0..576
    if (cb == 576) {   // bias [0 | bk | bv], 2304 wide
      #pragma unroll
      for (int i = 0; i < 9; ++i) {
        int c = i * 256 + tid;
        if (c < 2304) kvb[c] = (c < 768) ? 0.f : (c < 1536 ? bk[c - 768] : bv[c - 1536]);
      }
      return;
    }
    const int wsel = cb / 144, rem = cb % 144;
    const float* W = wsel == 0 ? W0 : wsel == 1 ? W1 : wsel == 2 ? W2 : W3;
    short* dst = Wt + (size_t)wsel * 768 * 768;
    const int bn = rem % 12, bk2 = rem / 12;
    const int k0 = bk2 * 64, n0 = bn * 64;
    #pragma unroll
    for (int i = 0; i < 4; ++i) {
      int id = i * 256 + tid;
      int r = id >> 4, c4 = (id & 15) * 4;
      float4 w4 = *(const float4*)(W + (size_t)(k0 + r) * 768 + n0 + c4);
      T[c4 + 0][r] = f2bf(w4.x);
      T[c4 + 1][r] = f2bf(w4.y);
      T[c4 + 2][r] = f2bf(w4.z);
      T[c4 + 3][r] = f2bf(w4.w);
    }
    __syncthreads();
    #pragma unroll
    for (int i = 0; i < 4; ++i) {
      int id = i * 256 + tid;
      int nn = id >> 4, k4 = (id & 15) * 4;
      short4v s = *(const short4v*)&T[nn][k4];
      *(short4v*)(dst + (size_t)(n0 + nn) * 768 + k0 + k4) = s;
    }
    return;
  }

  if (blockIdx.x >= 2048) {   // temb rows of all_e
    int b = blockIdx.x - 2048;
    #pragma unroll
    for (int i = 0; i < 3; ++i)
      all_e[(size_t)b * KVr * Dd + tid + i * 256] = f2bf(temb[(size_t)b * Dd + tid + i * 256]);
    return;
  }
  const int row = blockIdx.x;
  const int b = row >> 10, s = row & 1023;
  const float* ap = l2r + (size_t)row * Dd;
  const float* cp = r2l + (size_t)row * Dd;
  float a0 = ap[tid], a1 = ap[tid + 256], a2 = ap[tid + 512];
  float c0 = cp[tid], c1 = cp[tid + 256], c2 = cp[tid + 512];
  float ma = blk_sum(a0 + a1 + a2, sh) * (1.f / 768.f);
  float mc = blk_sum(c0 + c1 + c2, sh) * (1.f / 768.f);
  float va = blk_sum((a0-ma)*(a0-ma) + (a1-ma)*(a1-ma) + (a2-ma)*(a2-ma), sh) * (1.f / 768.f);
  float vc = blk_sum((c0-mc)*(c0-mc) + (c1-mc)*(c1-mc) + (c2-mc)*(c2-mc), sh) * (1.f / 768.f);
  float ia = rsqrtf(va + 1e-6f), ic = rsqrtf(vc + 1e-6f);
  size_t ro = (size_t)row * Dd;
  size_t e1 = ((size_t)b * KVr + 1 + s) * Dd;
  size_t e2 = ((size_t)b * KVr + 1 + Ss + s) * Dd;
  float av[3] = {a0, a1, a2}, cv[3] = {c0, c1, c2};
  #pragma unroll
  for (int i = 0; i < 3; ++i) {
    int c = tid + i * 256;
    float an = (av[i] - ma) * ia * s1[c] + b1[c];
    float cn = (cv[i] - mc) * ic * s2[c] + b2[c];
    inputs[ro + c] = av[i] + cv[i];
    all_e[e1 + c]  = f2bf(an);
    all_e[e2 + c]  = f2bf(cn);
  }
}

// ---------------- split-K(2) combine + bias + residual + LN (wo path) ----------------
__global__ __launch_bounds__(256) void ln_comb2(
    const float* __restrict__ pk,
    const float* __restrict__ bias, const float* __restrict__ res,
    const float* __restrict__ sc, const float* __restrict__ bi,
    float* __restrict__ yf, short* __restrict__ yb)
{
  __shared__ float sh[4];
  const int row = blockIdx.x, tid = threadIdx.x;
  const size_t PS = (size_t)2048 * 768;
  size_t ro = (size_t)row * Dd;
  float vv[3];
  #pragma unroll
  for (int i = 0; i < 3; ++i) {
    int c = tid + i * 256;
    vv[i] = pk[ro + c] + pk[PS + ro + c] + bias[c] + res[ro + c];
  }
  float m = blk_sum(vv[0] + vv[1] + vv[2], sh) * (1.f / 768.f);
  float var = blk_sum((vv[0]-m)*(vv[0]-m) + (vv[1]-m)*(vv[1]-m) + (vv[2]-m)*(vv[2]-m), sh) * (1.f / 768.f);
  float inv = rsqrtf(var + 1e-6f);
  #pragma unroll
  for (int i = 0; i < 3; ++i) {
    int c = tid + i * 256;
    yf[ro + c] = vv[i];
    yb[ro + c] = f2bf((vv[i] - m) * inv * sc[c] + bi[c]);
  }
}

// ---------------- split-K(4) combine + LN + FiLM (standalone, r1) ----------------
__global__ __launch_bounds__(256) void ln_comb(
    const float* __restrict__ pk,
    const float* __restrict__ bias, const float* __restrict__ res,
    const float* __restrict__ sc, const float* __restrict__ bi,
    const float* __restrict__ film, float* __restrict__ yf, short* __restrict__ yb)
{
  __shared__ float sh[4];
  const int row = blockIdx.x, tid = threadIdx.x;
  const size_t PS = (size_t)2048 * 768;
  size_t ro = (size_t)row * Dd;
  float vv[3];
  #pragma unroll
  for (int i = 0; i < 3; ++i) {
    int c = tid + i * 256;
    float v = bias[c] + res[ro + c];
    #pragma unroll
    for (int s = 0; s < 4; ++s) v += pk[s * PS + ro + c];
    vv[i] = v;
  }
  float m = blk_sum(vv[0] + vv[1] + vv[2], sh) * (1.f / 768.f);
  float var = blk_sum((vv[0]-m)*(vv[0]-m) + (vv[1]-m)*(vv[1]-m) + (vv[2]-m)*(vv[2]-m), sh) * (1.f / 768.f);
  float inv = rsqrtf(var + 1e-6f);
  int bb = row >> 10;
  #pragma unroll
  for (int i = 0; i < 3; ++i) {
    int c = tid + i * 256;
    float o = (vv[i] - m) * inv * sc[c] + bi[c];
    o = film[(size_t)bb * 1536 + c] * o + film[(size_t)bb * 1536 + 768 + c];
    if (yf) yf[ro + c] = o;
    if (yb) yb[ro + c] = f2bf(o);
  }
}

// ---------------- merged: combine(ff) [0-2047] + convT2(r0) [2048-3199] ----------------
__global__ __launch_bounds__(256) void comb_convT2(
    const float* __restrict__ pk, const float* __restrict__ bias, const float* __restrict__ res,
    float* __restrict__ yf, short* __restrict__ yb,
    const float* __restrict__ W1, short* __restrict__ D1,
    const float* __restrict__ W2, short* __restrict__ D2)
{
  const int tid = threadIdx.x;
  if (blockIdx.x >= 2048) {
    __shared__ short T[64][72];
    const int id = blockIdx.x - 2048;
    const bool second = id >= 576;
    const int id576 = second ? (id - 576) : id;
    const int K = second ? 3072 : 768;
    const int N = second ? 768 : 3072;
    const int ntile = N >> 6;
    const float* W = second ? W2 : W1;
    short* Wt = second ? D2 : D1;
    const int bn = id576 % ntile, bk = id576 / ntile;
    const int k0 = bk * 64, n0 = bn * 64;
    #pragma unroll
    for (int i = 0; i < 4; ++i) {
      int jd = i * 256 + tid;
      int r = jd >> 4, c4 = (jd & 15) * 4;
      float4 w4 = *(const float4*)(W + (size_t)(k0 + r) * N + n0 + c4);
      T[c4 + 0][r] = f2bf(w4.x);
      T[c4 + 1][r] = f2bf(w4.y);
      T[c4 + 2][r] = f2bf(w4.z);
      T[c4 + 3][r] = f2bf(w4.w);
    }
    __syncthreads();
    #pragma unroll
    for (int i = 0; i < 4; ++i) {
      int jd = i * 256 + tid;
      int nn = jd >> 4, k4 = (jd & 15) * 4;
      short4v s = *(const short4v*)&T[nn][k4];
      *(short4v*)(Wt + (size_t)(n0 + nn) * K + k0 + k4) = s;
    }
    return;
  }
  const int row = blockIdx.x;
  const size_t PS = (size_t)2048 * 768;
  size_t ro = (size_t)row * Dd;
  #pragma unroll
  for (int i = 0; i < 3; ++i) {
    int c = tid + i * 256;
    float v = bias[c] + res[ro + c];
    #pragma unroll
    for (int s = 0; s < 4; ++s) v += pk[s * PS + ro + c];
    yf[ro + c] = v;
    yb[ro + c] = f2bf(v);
  }
}

// ---------------- merged: ln_comb(r0) [0-2047] + convT2(r1) [2048-3199] ----------------
__global__ __launch_bounds__(256) void lncomb_convT2(
    const float* __restrict__ pk, const float* __restrict__ bias, const float* __restrict__ res,
    const float* __restrict__ sc, const float* __restrict__ bi,
    const float* __restrict__ film, float* __restrict__ yf, short* __restrict__ yb,
    const float* __restrict__ W1, short* __restrict__ D1,
    const float* __restrict__ W2, short* __restrict__ D2)
{
  const int tid = threadIdx.x;
  if (blockIdx.x >= 2048) {
    __shared__ short T[64][72];
    const int id = blockIdx.x - 2048;
    const bool second = id >= 576;
    const int id576 = second ? (id - 576) : id;
    const int K = second ? 3072 : 768;
    const int N = second ? 768 : 3072;
    const int ntile = N >> 6;
    const float* W = second ? W2 : W1;
    short* Wt = second ? D2 : D1;
    const int bn = id576 % ntile, bk = id576 / ntile;
    const int k0 = bk * 64, n0 = bn * 64;
    #pragma unroll
    for (int i = 0; i < 4; ++i) {
      int jd = i * 256 + tid;
      int r = jd >> 4, c4 = (jd & 15) * 4;
      float4 w4 = *(const float4*)(W + (size_t)(k0 + r) * N + n0 + c4);
      T[c4 + 0][r] = f2bf(w4.x);
      T[c4 + 1][r] = f2bf(w4.y);
      T[c4 + 2][r] = f2bf(w4.z);
      T[c4 + 3][r] = f2bf(w4.w);
    }
    __syncthreads();
    #pragma unroll
    for (int i = 0; i < 4; ++i) {
      int jd = i * 256 + tid;
      int nn = jd >> 4, k4 = (jd & 15) * 4;
      short4v s = *(const short4v*)&T[nn][k4];
      *(short4v*)(Wt + (size_t)(n0 + nn) * K + k0 + k4) = s;
    }
    return;
  }
  __shared__ float sh[4];
  const int row = blockIdx.x;
  const size_t PS = (size_t)2048 * 768;
  size_t ro = (size_t)row * Dd;
  float vv[3];
  #pragma unroll
  for (int i = 0; i < 3; ++i) {
    int c = tid + i * 256;
    float v = bias[c] + res[ro + c];
    #pragma unroll
    for (int s = 0; s < 4; ++s) v += pk[s * PS + ro + c];
    vv[i] = v;
  }
  float m = blk_sum(vv[0] + vv[1] + vv[2], sh) * (1.f / 768.f);
  float var = blk_sum((vv[0]-m)*(vv[0]-m) + (vv[1]-m)*(vv[1]-m) + (vv[2]-m)*(vv[2]-m), sh) * (1.f / 768.f);
  float inv = rsqrtf(var + 1e-6f);
  int bb = row >> 10;
  #pragma unroll
  for (int i = 0; i < 3; ++i) {
    int c = tid + i * 256;
    float o = (vv[i] - m) * inv * sc[c] + bi[c];
    o = film[(size_t)bb * 1536 + c] * o + film[(size_t)bb * 1536 + 768 + c];
    yf[ro + c] = o;
    yb[ro + c] = f2bf(o);
  }
}

// ---------------- plain convT (out_w) and convT2 (ff) ----------------
__global__ __launch_bounds__(256) void convT(const float* __restrict__ W, short* __restrict__ Wt,
                                             int K, int N, int ntile)
{
  __shared__ short T[64][72];
  const int bn = blockIdx.x % ntile, bk = blockIdx.x / ntile;
  const int k0 = bk * 64, n0 = bn * 64, tid = threadIdx.x;
  #pragma unroll
  for (int i = 0; i < 4; ++i) {
    int id = i * 256 + tid;
    int r = id >> 4, c4 = (id & 15) * 4;
    float4 w4 = *(const float4*)(W + (size_t)(k0 + r) * N + n0 + c4);
    T[c4 + 0][r] = f2bf(w4.x);
    T[c4 + 1][r] = f2bf(w4.y);
    T[c4 + 2][r] = f2bf(w4.z);
    T[c4 + 3][r] = f2bf(w4.w);
  }
  __syncthreads();
  #pragma unroll
  for (int i = 0; i < 4; ++i) {
    int id = i * 256 + tid;
    int n = id >> 4, k4 = (id & 15) * 4;
    short4v s = *(const short4v*)&T[n][k4];
    *(short4v*)(Wt + (size_t)(n0 + n) * K + k0 + k4) = s;
  }
}

__global__ __launch_bounds__(256) void convT2(const float* __restrict__ W1, short* __restrict__ D1,
                                              const float* __restrict__ W2, short* __restrict__ D2)
{
  __shared__ short T[64][72];
  const int tid = threadIdx.x;
  const bool second = blockIdx.x >= 576;
  const int id576 = second ? (blockIdx.x - 576) : blockIdx.x;
  const int K = second ? 3072 : 768;
  const int N = second ? 768 : 3072;
  const int ntile = N >> 6;
  const float* W = second ? W2 : W1;
  short* Wt = second ? D2 : D1;
  const int bn = id576 % ntile, bk = id576 / ntile;
  const int k0 = bk * 64, n0 = bn * 64;
  #pragma unroll
  for (int i = 0; i < 4; ++i) {
    int id = i * 256 + tid;
    int r = id >> 4, c4 = (id & 15) * 4;
    float4 w4 = *(const float4*)(W + (size_t)(k0 + r) * N + n0 + c4);
    T[c4 + 0][r] = f2bf(w4.x);
    T[c4 + 1][r] = f2bf(w4.y);
    T[c4 + 2][r] = f2bf(w4.z);
    T[c4 + 3][r] = f2bf(w4.w);
  }
  __syncthreads();
  #pragma unroll
  for (int i = 0; i < 4; ++i) {
    int id = i * 256 + tid;
    int n = id >> 4, k4 = (id & 15) * 4;
    short4v s = *(const short4v*)&T[n][k4];
    *(short4v*)(Wt + (size_t)(n0 + n) * K + k0 + k4) = s;
  }
}

// ---------------- 128x128 bf16 GEMM, BK=32 dbuf, 4 blocks/CU ----------------
template<int ACT>
__global__ __launch_bounds__(256, 4) void gemm_bf(
    const short* __restrict__ A, const short* __restrict__ Bt,
    const float* __restrict__ bias, const float* __restrict__ res,
    float* __restrict__ C, short* __restrict__ Cbf, float* __restrict__ Cpart,
    int M, int N, int K, float scale, int mtiles, int ntiles, int ksplit)
{
  __shared__ short As[2][4096];
  __shared__ short Bs[2][4096];
  const int tid = threadIdx.x, lane = tid & 63, wv = tid >> 6;
  const int l15 = lane & 15, l4 = lane >> 4;

  const int nwg = gridDim.x;
  const int qc = nwg >> 3, rc = nwg & 7;
  const int xcd = blockIdx.x & 7, idx = blockIdx.x >> 3;
  const int wgid = (xcd < rc ? xcd * (qc + 1) : rc * (qc + 1) + (xcd - rc) * qc) + idx;
  const int by = wgid % mtiles;
  const int rest = wgid / mtiles;
  const int bx = rest % ntiles;
  const int sp = rest / ntiles;
  const int kper = K / ksplit;
  const int kbeg = sp * kper;
  const int NT = kper >> 5;

  const int m0 = by * 128, n0 = bx * 128;
  const int wm = (wv >> 1) * 64, wn = (wv & 1) * 64;

  const int srow = lane >> 2, schunk = lane & 3;
  const int scsw = (schunk ^ ((srow >> 1) & 3)) << 3;
  const short* sA = A + (size_t)(m0 + wv * 32 + srow) * K + kbeg + scsw;
  const short* sB = Bt + (size_t)(n0 + wv * 32 + srow) * K + kbeg + scsw;
  const int stBase = wv * 1024;
  const int frsw = (l4 ^ ((l15 >> 1) & 3)) << 3;

  f32x4 acc[4][4];
  const f32x4 zz = {0.f, 0.f, 0.f, 0.f};
  #pragma unroll
  for (int i = 0; i < 4; ++i)
    #pragma unroll
    for (int j = 0; j < 4; ++j) acc[i][j] = zz;

  GL16(sA, &As[0][stBase]);
  GL16(sA + (size_t)16 * K, &As[0][stBase + 512]);
  GL16(sB, &Bs[0][stBase]);
  GL16(sB + (size_t)16 * K, &Bs[0][stBase + 512]);

  int buf = 0;
  for (int t = 0; t < NT; ++t) {
    if (t + 1 < NT) {
      int k0 = (t + 1) << 5;
      GL16(sA + k0, &As[buf ^ 1][stBase]);
      GL16(sA + (size_t)16 * K + k0, &As[buf ^ 1][stBase + 512]);
      GL16(sB + k0, &Bs[buf ^ 1][stBase]);
      GL16(sB + (size_t)16 * K + k0, &Bs[buf ^ 1][stBase + 512]);
      asm volatile("s_waitcnt vmcnt(4)" ::: "memory");
    } else {
      asm volatile("s_waitcnt vmcnt(0)" ::: "memory");
    }
    __builtin_amdgcn_s_barrier();

    short8v af[4], bfv[4];
    #pragma unroll
    for (int mi = 0; mi < 4; ++mi)
      af[mi] = *(const short8v*)&As[buf][(wm + mi * 16 + l15) * 32 + frsw];
    #pragma unroll
    for (int ni = 0; ni < 4; ++ni)
      bfv[ni] = *(const short8v*)&Bs[buf][(wn + ni * 16 + l15) * 32 + frsw];
    __builtin_amdgcn_s_setprio(1);
    #pragma unroll
    for (int mi = 0; mi < 4; ++mi)
      #pragma unroll
      for (int ni = 0; ni < 4; ++ni)
        acc[mi][ni] = __builtin_amdgcn_mfma_f32_16x16x32_bf16(af[mi], bfv[ni], acc[mi][ni], 0, 0, 0);
    __builtin_amdgcn_s_setprio(0);
    if (t + 1 < NT) __builtin_amdgcn_s_barrier();
    buf ^= 1;
  }

  if (Cpart) {
    float* Cp = Cpart + (size_t)sp * M * N;
    #pragma unroll
    for (int mi = 0; mi < 4; ++mi)
      #pragma unroll
      for (int r = 0; r < 4; ++r) {
        int row = m0 + wm + mi * 16 + l4 * 4 + r;
        if (row >= M) continue;
        size_t rb = (size_t)row * N;
        #pragma unroll
        for (int ni = 0; ni < 4; ++ni)
          Cp[rb + n0 + wn + ni * 16 + l15] = acc[mi][ni][r];
      }
    return;
  }

  #pragma unroll
  for (int mi = 0; mi < 4; ++mi) {
    #pragma unroll
    for (int r = 0; r < 4; ++r) {
      int row = m0 + wm + mi * 16 + l4 * 4 + r;
      if (row >= M) continue;
      size_t rb = (size_t)row * N;
      #pragma unroll
      for (int ni = 0; ni < 4; ++ni) {
        int col = n0 + wn + ni * 16 + l15;
        float val = (acc[mi][ni][r] + bias[col]) * scale;
        if (ACT == 1) val = fmaxf(val, 0.f);
        if (ACT == 2) val = gelu_f(val);
        if (res) val += res[rb + col];
        if (C)   C[rb + col] = val;
        if (Cbf) Cbf[rb + col] = f2bf(val);
      }
    }
  }
}

// ---------------- 256x256 / 8-wave / BK=64 / 4-phase, 2 barriers/tile (vocab) ----------------
__global__ __launch_bounds__(512, 2) void gemm256(
    const short* __restrict__ A, const short* __restrict__ Bt,
    const float* __restrict__ bias, float* __restrict__ C,
    int M, int N, int K, int mtiles)
{
  __shared__ short As[2][16384];
  __shared__ short Bs[2][16384];
  const int tid = threadIdx.x, lane = tid & 63, wv = tid >> 6;
  const int l15 = lane & 15, l4 = lane >> 4;

  const int nwg = gridDim.x;
  const int qc = nwg >> 3, rc = nwg & 7;
  const int xcd = blockIdx.x & 7, idx = blockIdx.x >> 3;
  const int wgid = (xcd < rc ? xcd * (qc + 1) : rc * (qc + 1) + (xcd - rc) * qc) + idx;
  const int by = wgid % mtiles, bx = wgid / mtiles;
  const int m0 = by * 256, n0 = bx * 256;
  const int wm = (wv >> 2) * 128, wn = (wv & 3) * 64;

  const int srow = lane >> 2, schunk = lane & 3;
  const int scsw = (schunk ^ ((srow >> 1) & 3)) << 3;
  const short* sA = A + (size_t)(m0 + wv * 16 + srow) * K + scsw;
  const short* sB = Bt + (size_t)(n0 + wv * 16 + srow) * K + scsw;
  const int stBase = wv * 512;
  const int frsw = (l4 ^ ((l15 >> 1) & 3)) << 3;

  #define STG_A(b, kk, ko) do { \
    GL16(sA + (ko) + (kk) * 32,                  &As[b][(kk) * 8192 + stBase]); \
    GL16(sA + (size_t)128 * K + (ko) + (kk) * 32, &As[b][(kk) * 8192 + 4096 + stBase]); } while (0)
  #define STG_B(b, kk, ko) do { \
    GL16(sB + (ko) + (kk) * 32,                  &Bs[b][(kk) * 8192 + stBase]); \
    GL16(sB + (size_t)128 * K + (ko) + (kk) * 32, &Bs[b][(kk) * 8192 + 4096 + stBase]); } while (0)
  #define ARD(b, kk, row) (*(const short8v*)&As[b][(kk) * 8192 + (row) * 32 + frsw])
  #define BRD(b, kk, row) (*(const short8v*)&Bs[b][(kk) * 8192 + (row) * 32 + frsw])

  f32x4 acc[8][4];
  const f32x4 zz = {0.f, 0.f, 0.f, 0.f};
  #pragma unroll
  for (int i = 0; i < 8; ++i)
    #pragma unroll
    for (int j = 0; j < 4; ++j) acc[i][j] = zz;

  const int NT = K >> 6;

  STG_A(0, 0, 0); STG_B(0, 0, 0); STG_A(0, 1, 0); STG_B(0, 1, 0);
  asm volatile("s_waitcnt vmcnt(4)" ::: "memory");
  __builtin_amdgcn_s_barrier();

  int buf = 0;
  for (int t = 0; t < NT; ++t) {
    const bool pf = (t + 1 < NT);
    const int k1 = (t + 1) << 6;
    short8v af[4], bfv[4];

    #pragma unroll
    for (int mi = 0; mi < 4; ++mi) af[mi] = ARD(buf, 0, wm + mi * 16 + l15);
    #pragma unroll
    for (int ni = 0; ni < 4; ++ni) bfv[ni] = BRD(buf, 0, wn + ni * 16 + l15);
    if (pf) STG_A(buf ^ 1, 0, k1);
    asm volatile("s_waitcnt lgkmcnt(0)" ::: "memory");
    __builtin_amdgcn_sched_barrier(0);
    __builtin_amdgcn_s_setprio(1);
    #pragma unroll
    for (int mi = 0; mi < 4; ++mi)
      #pragma unroll
      for (int ni = 0; ni < 4; ++ni)
        acc[mi][ni] = __builtin_amdgcn_mfma_f32_16x16x32_bf16(af[mi], bfv[ni], acc[mi][ni], 0, 0, 0);
    __builtin_amdgcn_s_setprio(0);

    #pragma unroll
    for (int mi = 0; mi < 4; ++mi) af[mi] = ARD(buf, 0, wm + 64 + mi * 16 + l15);
    if (pf) STG_B(buf ^ 1, 0, k1);
    asm volatile("s_waitcnt lgkmcnt(0)" ::: "memory");
    __builtin_amdgcn_sched_barrier(0);
    __builtin_amdgcn_s_setprio(1);
    #pragma unroll
    for (int mi = 0; mi < 4; ++mi)
      #pragma unroll
      for (int ni = 0; ni < 4; ++ni)
        acc[4 + mi][ni] = __builtin_amdgcn_mfma_f32_16x16x32_bf16(af[mi], bfv[ni], acc[4 + mi][ni], 0, 0, 0);
    __builtin_amdgcn_s_setprio(0);
    if (pf) asm volatile("s_waitcnt vmcnt(4)" ::: "memory");
    else    asm volatile("s_waitcnt vmcnt(0)" ::: "memory");
    __builtin_amdgcn_s_barrier();

    #pragma unroll
    for (int mi = 0; mi < 4; ++mi) af[mi] = ARD(buf, 1, wm + mi * 16 + l15);
    #pragma unroll
    for (int ni = 0; ni < 4; ++ni) bfv[ni] = BRD(buf, 1, wn + ni * 16 + l15);
    if (pf) STG_A(buf ^ 1, 1, k1);
    asm volatile("s_waitcnt lgkmcnt(0)" ::: "memory");
    __builtin_amdgcn_sched_barrier(0);
    __builtin_amdgcn_s_setprio(1);
    #pragma unroll
    for (int mi = 0; mi < 4; ++mi)
      #pragma unroll
      for (int ni = 0; ni < 4; ++ni)
        acc[mi][ni] = __builtin_amdgcn_mfma_f32_16x16x32_bf16(af[mi], bfv[ni], acc[mi][ni], 0, 0, 0);
    __builtin_amdgcn_s_setprio(0);

    #pragma unroll
    for (int mi = 0; mi < 4; ++mi) af[mi] = ARD(buf, 1, wm + 64 + mi * 16 + l15);
    if (pf) STG_B(buf ^ 1, 1, k1);
    asm volatile("s_waitcnt lgkmcnt(0)" ::: "memory");
    __builtin_amdgcn_sched_barrier(0);
    __builtin_amdgcn_s_setprio(1);
    #pragma unroll
    for (int mi = 0; mi < 4; ++mi)
      #pragma unroll
      for (int ni = 0; ni < 4; ++ni)
        acc[4 + mi][ni] = __builtin_amdgcn_mfma_f32_16x16x32_bf16(af[mi], bfv[ni], acc[4 + mi][ni], 0, 0, 0);
    __builtin_amdgcn_s_setprio(0);
    if (pf) {
      asm volatile("s_waitcnt vmcnt(4)" ::: "memory");
      __builtin_amdgcn_s_barrier();
    }
    buf ^= 1;
  }

  #pragma unroll
  for (int mi = 0; mi < 8; ++mi) {
    #pragma unroll
    for (int r = 0; r < 4; ++r) {
      int row = m0 + wm + mi * 16 + l4 * 4 + r;
      size_t rb = (size_t)row * N;
      #pragma unroll
      for (int ni = 0; ni < 4; ++ni) {
        int col = n0 + wn + ni * 16 + l15;
        C[rb + col] = acc[mi][ni][r] + bias[col];
      }
    }
  }
  #undef STG_A
  #undef STG_B
  #undef ARD
  #undef BRD
}

// ---------------- flash attention, 4-chunk KV-split, q assembled in-kernel ----------------
__global__ __launch_bounds__(256) void attn_kernel(
    const short* __restrict__ kvq, const float* __restrict__ bq,
    float* __restrict__ Op0, float* __restrict__ Op1,
    float* __restrict__ Op2, float* __restrict__ Op3, float* __restrict__ ml)
{
  __shared__ short Kls[64][104];
  __shared__ short Vt[96][72];
  __shared__ short Pls[4][16][72];

  const int tid = threadIdx.x, lane = tid & 63, w = tid >> 6;
  const int l15 = lane & 15, l4 = lane >> 4;
  const int chunk = blockIdx.x >> 8;
  const int inner = blockIdx.x & 255;
  const int qt = inner & 15;
  const int bh = inner >> 4;
  const int h = bh & 7, b = bh >> 3;
  const int qb = qt * 64;
  const int qw = qb + w * 16;
  const float qsc = 0.1020620726159658f;   // 1/sqrt(96)

  short8v qf[3];
  {
    const short* p1 = kvq + ((size_t)b * KVr + 1 + qw + l15) * 2304 + h * HDh + l4 * 8;
    const short* p2 = p1 + (size_t)Ss * 2304;
    #pragma unroll
    for (int kk = 0; kk < 3; ++kk) {
      short8v a8 = *(const short8v*)(p1 + kk * 32);
      short8v b8 = *(const short8v*)(p2 + kk * 32);
      short8v tq;
      #pragma unroll
      for (int j = 0; j < 8; ++j)
        tq[j] = f2bf((bf2f(a8[j]) + bf2f(b8[j]) + bq[h * HDh + kk * 32 + l4 * 8 + j]) * qsc);
      qf[kk] = tq;
    }
  }

  const f32x4 zz = {0.f, 0.f, 0.f, 0.f};
  f32x4 Oa[6];
  #pragma unroll
  for (int fn = 0; fn < 6; ++fn) Oa[fn] = zz;
  float mrow[4], lrow[4];
  #pragma unroll
  for (int r = 0; r < 4; ++r) { mrow[r] = -3.0e38f; lrow[r] = 0.f; }

  const size_t kvbase = (size_t)b * KVr;

  for (int t = chunk; t < 33; t += 4) {
    int k0 = t * 64;
    bool l2r_vis = (k0 <= Ss) && (k0 - 1 <= qb + 63);
    int rmaxk = (k0 + 63 > 2 * Ss) ? 2 * Ss : (k0 + 63);
    bool r2l_vis = (k0 + 63 >= Ss + 1) && (rmaxk - (Ss + 1) >= qb);
    if (!(t == 0 || l2r_vis || r2l_vis)) continue;

    __syncthreads();
    #pragma unroll
    for (int i = 0; i < 3; ++i) {
      int id = i * 256 + tid;
      int row = id / 12, cc = (id % 12) * 8;
      int key = k0 + row;
      if (key > 2 * Ss) key = 2 * Ss;
      const short* kp = kvq + (kvbase + key) * 2304 + 768 + h * HDh + cc;
      short8v k8 = *(const short8v*)kp;
      *(short8v*)&Kls[row][cc] = k8;
      short8v v8 = *(const short8v*)(kp + 768);
      #pragma unroll
      for (int j = 0; j < 8; ++j) Vt[cc + j][row] = v8[j];
    }
    __syncthreads();

    f32x4 sc[4];
    #pragma unroll
    for (int nt = 0; nt < 4; ++nt) {
      f32x4 d = zz;
      #pragma unroll
      for (int kk = 0; kk < 3; ++kk) {
        short8v kf = *(const short8v*)&Kls[nt * 16 + l15][kk * 32 + l4 * 8];
        d = __builtin_amdgcn_mfma_f32_16x16x32_bf16(qf[kk], kf, d, 0, 0, 0);
      }
      sc[nt] = d;
    }
    float tmax[4] = {-3.0e38f, -3.0e38f, -3.0e38f, -3.0e38f};
    #pragma unroll
    for (int nt = 0; nt < 4; ++nt)
      #pragma unroll
      for (int r = 0; r < 4; ++r) {
        int qg = qw + l4 * 4 + r;
        int j = k0 + nt * 16 + l15;
        bool vis = (j == 0) ||
                   (j >= 1 && j <= Ss && (j - 1) <= qg) ||
                   (j >= Ss + 1 && j <= 2 * Ss && (j - (Ss + 1)) >= qg);
        if (!vis) sc[nt][r] = -3.0e38f;
        tmax[r] = fmaxf(tmax[r], sc[nt][r]);
      }
    #pragma unroll
    for (int r = 0; r < 4; ++r) {
      #pragma unroll
      for (int off = 8; off >= 1; off >>= 1) tmax[r] = fmaxf(tmax[r], __shfl_xor(tmax[r], off));
    }
    float scl[4];
    #pragma unroll
    for (int r = 0; r < 4; ++r) {
      float mnew = fmaxf(mrow[r], tmax[r]);
      scl[r] = __expf(mrow[r] - mnew);
      mrow[r] = mnew;
    }
    #pragma unroll
    for (int fn = 0; fn < 6; ++fn)
      #pragma unroll
      for (int r = 0; r < 4; ++r) Oa[fn][r] *= scl[r];
    float lad[4] = {0.f, 0.f, 0.f, 0.f};
    #pragma unroll
    for (int nt = 0; nt < 4; ++nt)
      #pragma unroll
      for (int r = 0; r < 4; ++r) {
        float p = __expf(sc[nt][r] - mrow[r]);
        lad[r] += p;
        Pls[w][l4 * 4 + r][nt * 16 + l15] = f2bf(p);
      }
    #pragma unroll
    for (int r = 0; r < 4; ++r) {
      #pragma unroll
      for (int off = 8; off >= 1; off >>= 1) lad[r] += __shfl_xor(lad[r], off);
      lrow[r] = lrow[r] * scl[r] + lad[r];
    }
    __syncthreads();

    short8v pf[2];
    #pragma unroll
    for (int kk = 0; kk < 2; ++kk) pf[kk] = *(const short8v*)&Pls[w][l15][kk * 32 + l4 * 8];
    #pragma unroll
    for (int fn = 0; fn < 6; ++fn) {
      #pragma unroll
      for (int kk = 0; kk < 2; ++kk) {
        short8v vf = *(const short8v*)&Vt[fn * 16 + l15][kk * 32 + l4 * 8];
        Oa[fn] = __builtin_amdgcn_mfma_f32_16x16x32_bf16(pf[kk], vf, Oa[fn], 0, 0, 0);
      }
    }
  }

  float* Op = (chunk == 0) ? Op0 : (chunk == 1) ? Op1 : (chunk == 2) ? Op2 : Op3;
  #pragma unroll
  for (int fn = 0; fn < 6; ++fn)
    #pragma unroll
    for (int r = 0; r < 4; ++r) {
      int row = qw + l4 * 4 + r;
      int col = h * HDh + fn * 16 + l15;
      Op[((size_t)(b * Ss + row)) * Dd + col] = Oa[fn][r];
    }
  if (l15 == 0) {
    #pragma unroll
    for (int r = 0; r < 4; ++r) {
      int row = qw + l4 * 4 + r;
      size_t ix = (size_t)chunk * 32768 + (((size_t)(b * 8 + h) * 1024 + row) * 2);
      ml[ix] = mrow[r];
      ml[ix + 1] = lrow[r];
    }
  }
}

// online-softmax merge of the 4 KV chunks -> attn_bf
__global__ __launch_bounds__(256) void attn_merge(
    const float* __restrict__ Op0, const float* __restrict__ Op1,
    const float* __restrict__ Op2, const float* __restrict__ Op3,
    const float* __restrict__ ml, short* __restrict__ o)
{
  const int row = blockIdx.x, tid = threadIdx.x;
  const int b = row >> 10, s = row & 1023;
  size_t ro = (size_t)row * Dd;
  #pragma unroll
  for (int i = 0; i < 3; ++i) {
    int c = tid + i * 256;
    int h = c / HDh;
    size_t ix = ((size_t)(b * 8 + h) * 1024 + s) * 2;
    float m0 = ml[ix], l0 = ml[ix + 1];
    float m1 = ml[32768 + ix], l1 = ml[32768 + ix + 1];
    float m2 = ml[65536 + ix], l2 = ml[65536 + ix + 1];
    float m3 = ml[98304 + ix], l3 = ml[98304 + ix + 1];
    float mm = fmaxf(fmaxf(m0, m1), fmaxf(m2, m3));
    float s0 = __expf(m0 - mm), s1 = __expf(m1 - mm);
    float s2 = __expf(m2 - mm), s3 = __expf(m3 - mm);
    float denom = s0 * l0 + s1 * l1 + s2 * l2 + s3 * l3;
    float val = s0 * Op0[ro + c] + s1 * Op1[ro + c] + s2 * Op2[ro + c] + s3 * Op3[ro + c];
    o[ro + c] = f2bf(val / denom);
  }
}

// ---------------- launch helpers ----------------
static void gemm_launch(int act, const short* A, const short* Bt, const float* bias,
                        const float* res, float* C, short* Cbf, float* Cpart,
                        int M, int N, int K, float scale, int ksplit, hipStream_t s)
{
  int mt = (M + 127) >> 7, nt = N >> 7;
  dim3 grid(mt * nt * ksplit), blk(256);
  if (act == 1)      gemm_bf<1><<<grid, blk, 0, s>>>(A, Bt, bias, res, C, Cbf, Cpart, M, N, K, scale, mt, nt, ksplit);
  else if (act == 2) gemm_bf<2><<<grid, blk, 0, s>>>(A, Bt, bias, res, C, Cbf, Cpart, M, N, K, scale, mt, nt, ksplit);
  else               gemm_bf<0><<<grid, blk, 0, s>>>(A, Bt, bias, res, C, Cbf, Cpart, M, N, K, scale, mt, nt, ksplit);
}

extern "C" void kernel_launch(void* const* d_in, const int* in_sizes, int n_in,
                              void* d_out, int out_size, void* d_ws, size_t ws_size,
                              hipStream_t stream)
{
  (void)in_sizes; (void)n_in; (void)out_size; (void)ws_size;
  const float* l2r      = (const float*)d_in[0];
  const float* r2l      = (const float*)d_in[1];
  const float* temb     = (const float*)d_in[2];
  const float* ln_l2r_s = (const float*)d_in[3];
  const float* ln_l2r_b = (const float*)d_in[4];
  const float* ln_r2l_s = (const float*)d_in[5];
  const float* ln_r2l_b = (const float*)d_in[6];
  const float* Wq = (const float*)d_in[7];
  const float* bq = (const float*)d_in[8];
  const float* Wk = (const float*)d_in[9];
  const float* bk = (const float*)d_in[10];
  const float* Wv = (const float*)d_in[11];
  const float* bv = (const float*)d_in[12];
  const float* Wo = (const float*)d_in[13];
  const float* bo = (const float*)d_in[14];
  const float* ff_ln_s = (const float*)d_in[15];
  const float* ff_ln_b = (const float*)d_in[16];
  const float* ff_w1 = (const float*)d_in[17];
  const float* ff_b1 = (const float*)d_in[18];
  const float* ff_w2 = (const float*)d_in[19];
  const float* ff_b2 = (const float*)d_in[20];
  const float* tm_w1 = (const float*)d_in[21];
  const float* tm_b1 = (const float*)d_in[22];
  const float* tm_w2 = (const float*)d_in[23];
  const float* tm_b2 = (const float*)d_in[24];
  const float* film_w = (const float*)d_in[25];
  const float* film_b = (const float*)d_in[26];
  const float* r_w1 = (const float*)d_in[27];
  const float* r_b1 = (const float*)d_in[28];
  const float* r_w2 = (const float*)d_in[29];
  const float* r_b2 = (const float*)d_in[30];
  const float* r_ln_s = (const float*)d_in[31];
  const float* r_ln_b = (const float*)d_in[32];
  const float* out_w = (const float*)d_in[33];
  const float* out_b = (const float*)d_in[34];

  uint8_t* base = (uint8_t*)d_ws;
  // layout identical to round 13 (liveness-verified)
  short* alle_bf = (short*)(base + 3145728);
  short* kvq     = (short*)(base + 9440256);    // ends 28,323,840
  short* attn_bf = (short*)(base + 12585984);
  float* inputs  = (float*)(base + 28323840);
  float* xbuf    = (float*)(base + 34615296);
  short* xn_bf   = (short*)(base + 40906752);
  short* big_bf  = (short*)(base + 44052480);
  float* x2f     = (float*)(base + 56635392);
  short* x2bf    = (short*)(base + 62926848);
  float* x3f     = (float*)(base + 66072576);
  short* x3bf    = (short*)(base + 72364032);
  short* x4bf    = (short*)(base + 75509760);
  short* wslot   = (short*)(base + 78655488);
  uint8_t* sm    = base + 83374080;
  float* f0    = (float*)(sm + 0);
  float* f1    = (float*)(sm + 12288);
  float* kvbia = (float*)(sm + 24576);
  short* w2slot = (short*)inputs;
  float* part2a = (float*)(base + 44052480);
  float* part2b = (float*)(base + 44052480 + 1572864);
  float* part2c = (float*)(base + 44052480 + 3145728);
  float* Op0 = (float*)(base + 3145728);
  float* Op1 = xbuf;
  float* Op2 = (float*)(base + 44052480);
  float* Op3 = (float*)(base + 50343936);
  float* mlb = (float*)(base + 56635392);
  float* wopart = (float*)(base + 44052480);
  float* partK = (float*)(base + 0);
  short* outwT = (short*)(base + 0);

  dim3 blk(256);

  // 1. t-path as one cooperative kernel (thin1 -> thin1p -> film1p -> film2)
  {
    void* args[] = { (void*)&temb, (void*)&tm_w1, (void*)&tm_b1, (void*)&tm_w2, (void*)&tm_b2,
                     (void*)&film_w, (void*)&film_b,
                     (void*)&part2a, (void*)&part2b, (void*)&part2c, (void*)&f0, (void*)&f1 };
    hipLaunchCooperativeKernel((const void*)tpath_coop, dim3(768), blk, args, 0, stream);
  }

  // 2. prep + QKVO weight convert + bias concat
  prep_conv<<<dim3(2627), blk, 0, stream>>>(l2r, r2l, temb, ln_l2r_s, ln_l2r_b, ln_r2l_s, ln_r2l_b,
                                            inputs, alle_bf, Wq, Wk, Wv, Wo, bk, bv, wslot, kvbia);

  // 3. fused QKV projection: E[4098,768] @ [Wq|Wk|Wv] -> kvq[4098,2304] bf16
  gemm_launch(0, alle_bf, wslot, kvbia, nullptr, nullptr, kvq, nullptr, 4098, 2304, 768, 1.f, 1, stream);

  // 4-5. attention (q assembled in-kernel), 4 KV chunks + merge
  attn_kernel<<<dim3(1024), blk, 0, stream>>>(kvq, bq, Op0, Op1, Op2, Op3, mlb);
  attn_merge<<<dim3(2048), blk, 0, stream>>>(Op0, Op1, Op2, Op3, mlb, attn_bf);

  // 6-7. Wo projection split-K(2) + fused combine/residual/LN
  gemm_launch(0, attn_bf, wslot + (size_t)3 * 768 * 768, bo, nullptr, nullptr, nullptr, wopart, 2048, 768, 768, 1.f, 2, stream);
  ln_comb2<<<dim3(2048), blk, 0, stream>>>(wopart, bo, inputs, ff_ln_s, ff_ln_b, xbuf, xn_bf);

  // 8-10. ff block
  convT2<<<dim3(1152), blk, 0, stream>>>(ff_w1, wslot, ff_w2, w2slot);
  gemm_launch(1, xn_bf, wslot, ff_b1, nullptr, nullptr, big_bf, nullptr, 2048, 3072, 768, 1.f, 1, stream);
  gemm_launch(0, big_bf, w2slot, nullptr, nullptr, nullptr, nullptr, partK, 2048, 768, 3072, 1.f, 4, stream);

  // 11. combine(ff) + convT2(r0) merged
  comb_convT2<<<dim3(3200), blk, 0, stream>>>(partK, ff_b2, xbuf, x2f, x2bf,
                                              r_w1, wslot, r_w2, w2slot);

  // 12-13. residual block 0 GEMMs
  gemm_launch(2, x2bf, wslot, r_b1, nullptr, nullptr, big_bf, nullptr, 2048, 3072, 768, 1.f, 1, stream);
  gemm_launch(0, big_bf, w2slot, nullptr, nullptr, nullptr, nullptr, partK, 2048, 768, 3072, 1.f, 4, stream);

  // 14. ln_comb(r0) + convT2(r1) merged
  lncomb_convT2<<<dim3(3200), blk, 0, stream>>>(partK, r_b2, x2f, r_ln_s, r_ln_b, f0, x3f, x3bf,
                                                r_w1 + (size_t)768 * 3072, wslot,
                                                r_w2 + (size_t)3072 * 768, w2slot);

  // 15-16. residual block 1 GEMMs
  gemm_launch(2, x3bf, wslot, r_b1 + 3072, nullptr, nullptr, big_bf, nullptr, 2048, 3072, 768, 1.f, 1, stream);
  gemm_launch(0, big_bf, w2slot, nullptr, nullptr, nullptr, nullptr, partK, 2048, 768, 3072, 1.f, 4, stream);

  // 17. ln_comb(r1)
  ln_comb<<<dim3(2048), blk, 0, stream>>>(partK, r_b2 + 768, x3f, r_ln_s + 768, r_ln_b + 768, f1, nullptr, x4bf);

  // 18-19. vocab projection
  convT<<<dim3(6000), blk, 0, stream>>>(out_w, outwT, 768, 32000, 500);
  gemm256<<<dim3(8 * 125), dim3(512), 0, stream>>>(x4bf, outwT, out_b, (float*)d_out,
                                                   2048, 32000, 768, 8);
}

// Round 15
// 529.016 us; speedup vs baseline: 1.4161x; 1.4161x over previous
//
#include <hip/hip_runtime.h>
#include <cstdint>
#include <cstddef>

#define Bb 2
#define Ss 1024
#define Dd 768
#define Hh 8
#define HDh 96
#define Mm 3072
#define Vv 32000
#define KVr 2049   // 2S+1

typedef __attribute__((ext_vector_type(8))) short short8v;
typedef __attribute__((ext_vector_type(4))) short short4v;
typedef __attribute__((ext_vector_type(4))) float f32x4;

#define GL16(gp, lp) __builtin_amdgcn_global_load_lds( \
    (const __attribute__((address_space(1))) void*)(gp), \
    (__attribute__((address_space(3))) void*)(lp), 16, 0, 0)

static __device__ __forceinline__ short f2bf(float f) {
  union { float f; unsigned u; } x; x.f = f;
  unsigned r = (x.u + 0x7FFFu + ((x.u >> 16) & 1u)) >> 16;  // RNE
  return (short)(r & 0xFFFFu);
}

static __device__ __forceinline__ float bf2f(short s) {
  union { unsigned u; float f; } x; x.u = ((unsigned)(unsigned short)s) << 16;
  return x.f;
}

static __device__ __forceinline__ float gelu_f(float v) {
  float u = 0.7978845608028654f * (v + 0.044715f * v * v * v);
  float au = fabsf(u);
  float e = __expf(2.f * au);
  float t = 1.f - 2.f / (e + 1.f);     // tanh(|u|), safe at inf
  return 0.5f * v * (1.f + copysignf(t, u));
}

static __device__ __forceinline__ float blk_sum(float val, float* sh) {
  #pragma unroll
  for (int off = 32; off >= 1; off >>= 1) val += __shfl_xor(val, off);
  __syncthreads();
  if ((threadIdx.x & 63) == 0) sh[threadIdx.x >> 6] = val;
  __syncthreads();
  return sh[0] + sh[1] + sh[2] + sh[3];
}

// ---------------- thin (M=2) GEMM stage 1 ----------------
__global__ __launch_bounds__(256) void thin1(const float* __restrict__ A, const float* __restrict__ W,
                                             float* __restrict__ part, int K, int N, int nblk, int splits)
{
  __shared__ float a0s[64], a1s[64];
  const int nb = blockIdx.x % nblk, ks = blockIdx.x / nblk;
  const int kl = K / splits, kbeg = ks * kl;
  const int tid = threadIdx.x;
  for (int k = tid; k < kl; k += 256) { a0s[k] = A[kbeg + k]; a1s[k] = A[K + kbeg + k]; }
  __syncthreads();
  const int n = nb * 256 + tid;
  float acc0 = 0.f, acc1 = 0.f;
  for (int k = 0; k < kl; ++k) {
    float w = W[(size_t)(kbeg + k) * N + n];
    acc0 = fmaf(a0s[k], w, acc0);
    acc1 = fmaf(a1s[k], w, acc1);
  }
  part[(size_t)ks * 2 * N + n] = acc0;
  part[(size_t)ks * 2 * N + N + n] = acc1;
}

// thin GEMM stage 2: A rebuilt from previous partials (+bias, gelu), K=3072, N=3072
__global__ __launch_bounds__(256) void thin1p(
    const float* __restrict__ pin, const float* __restrict__ bin,
    const float* __restrict__ W, float* __restrict__ part)
{
  __shared__ float a0s[48], a1s[48];
  const int nb = blockIdx.x % 12, ks = blockIdx.x / 12;
  const int kbeg = ks * 48, tid = threadIdx.x;
  for (int j = tid; j < 96; j += 256) {
    int row = j / 48, k = j % 48;
    float v = bin[kbeg + k];
    for (int s = 0; s < 64; ++s) v += pin[(size_t)s * 6144 + (size_t)row * 3072 + kbeg + k];
    v = gelu_f(v);
    if (row) a1s[k] = v; else a0s[k] = v;
  }
  __syncthreads();
  const int n = nb * 256 + tid;
  float acc0 = 0.f, acc1 = 0.f;
  for (int k = 0; k < 48; ++k) {
    float w = W[(size_t)(kbeg + k) * 3072 + n];
    acc0 = fmaf(a0s[k], w, acc0);
    acc1 = fmaf(a1s[k], w, acc1);
  }
  part[(size_t)ks * 6144 + n] = acc0;
  part[(size_t)ks * 6144 + 3072 + n] = acc1;
}

// FiLM pair GEMM: A rebuilt from tm_w2 partials (+tm_b2, no act)
__global__ __launch_bounds__(256) void film1p(
    const float* __restrict__ pin, const float* __restrict__ bin,
    const float* __restrict__ W, float* __restrict__ part)
{
  __shared__ float a0s[48], a1s[48];
  const int nb = blockIdx.x % 12, ks = blockIdx.x / 12;
  const int kbeg = ks * 48, tid = threadIdx.x;
  for (int j = tid; j < 96; j += 256) {
    int row = j / 48, k = j % 48;
    float v = bin[kbeg + k];
    for (int s = 0; s < 64; ++s) v += pin[(size_t)s * 6144 + (size_t)row * 3072 + kbeg + k];
    if (row) a1s[k] = v; else a0s[k] = v;
  }
  __syncthreads();
  const int n = nb * 256 + tid;
  const int col = (n >= 1536) ? (n - 1536) : n;
  const float* Wp = W + ((n < 1536) ? (size_t)0 : (size_t)3072 * 1536)
                      + (size_t)kbeg * 1536 + col;
  float acc0 = 0.f, acc1 = 0.f;
  for (int k = 0; k < 48; ++k) {
    float w = Wp[(size_t)k * 1536];
    acc0 = fmaf(a0s[k], w, acc0);
    acc1 = fmaf(a1s[k], w, acc1);
  }
  part[(size_t)ks * 6144 + n] = acc0;
  part[(size_t)ks * 6144 + 3072 + n] = acc1;
}

// ---------------- prep (0-2049) + QKVO convert/bias (2050-2626) + film2 (2627-2638) ----------------
__global__ __launch_bounds__(256) void prep_conv(
    const float* __restrict__ l2r, const float* __restrict__ r2l,
    const float* __restrict__ temb,
    const float* __restrict__ s1, const float* __restrict__ b1,
    const float* __restrict__ s2, const float* __restrict__ b2,
    float* __restrict__ inputs, short* __restrict__ all_e,
    const float* __restrict__ W0, const float* __restrict__ W1,
    const float* __restrict__ W2, const float* __restrict__ W3,
    const float* __restrict__ bk, const float* __restrict__ bv,
    short* __restrict__ Wt, float* __restrict__ kvb,
    const float* __restrict__ part2c, const float* __restrict__ fb,
    float* __restrict__ f0, float* __restrict__ f1)
{
  __shared__ float sh[4];
  __shared__ short T[64][72];
  const int tid = threadIdx.x;

  if (blockIdx.x >= 2627) {   // film2 reduction (12 blocks)
    const int n = (blockIdx.x - 2627) * 256 + tid;
    float a0 = fb[n], a1 = a0;
    for (int s = 0; s < 64; ++s) {
      a0 += part2c[(size_t)s * 6144 + n];
      a1 += part2c[(size_t)s * 6144 + 3072 + n];
    }
    float* dst = (n < 1536) ? f0 : f1;
    const int c = (n >= 1536) ? (n - 1536) : n;
    dst[c] = a0;
    dst[1536 + c] = a1;
    return;
  }

  if (blockIdx.x >= 2050) {
    const int cb = blockIdx.x - 2050;   // 0..576
    if (cb == 576) {   // bias [0 | bk | bv], 2304 wide
      #pragma unroll
      for (int i = 0; i < 9; ++i) {
        int c = i * 256 + tid;
        if (c < 2304) kvb[c] = (c < 768) ? 0.f : (c < 1536 ? bk[c - 768] : bv[c - 1536]);
      }
      return;
    }
    const int wsel = cb / 144, rem = cb % 144;
    const float* W = wsel == 0 ? W0 : wsel == 1 ? W1 : wsel == 2 ? W2 : W3;
    short* dst = Wt + (size_t)wsel * 768 * 768;
    const int bn = rem % 12, bk2 = rem / 12;
    const int k0 = bk2 * 64, n0 = bn * 64;
    #pragma unroll
    for (int i = 0; i < 4; ++i) {
      int id = i * 256 + tid;
      int r = id >> 4, c4 = (id & 15) * 4;
      float4 w4 = *(const float4*)(W + (size_t)(k0 + r) * 768 + n0 + c4);
      T[c4 + 0][r] = f2bf(w4.x);
      T[c4 + 1][r] = f2bf(w4.y);
      T[c4 + 2][r] = f2bf(w4.z);
      T[c4 + 3][r] = f2bf(w4.w);
    }
    __syncthreads();
    #pragma unroll
    for (int i = 0; i < 4; ++i) {
      int id = i * 256 + tid;
      int nn = id >> 4, k4 = (id & 15) * 4;
      short4v s = *(const short4v*)&T[nn][k4];
      *(short4v*)(dst + (size_t)(n0 + nn) * 768 + k0 + k4) = s;
    }
    return;
  }

  if (blockIdx.x >= 2048) {   // temb rows of all_e
    int b = blockIdx.x - 2048;
    #pragma unroll
    for (int i = 0; i < 3; ++i)
      all_e[(size_t)b * KVr * Dd + tid + i * 256] = f2bf(temb[(size_t)b * Dd + tid + i * 256]);
    return;
  }
  const int row = blockIdx.x;
  const int b = row >> 10, s = row & 1023;
  const float* ap = l2r + (size_t)row * Dd;
  const float* cp = r2l + (size_t)row * Dd;
  float a0 = ap[tid], a1 = ap[tid + 256], a2 = ap[tid + 512];
  float c0 = cp[tid], c1 = cp[tid + 256], c2 = cp[tid + 512];
  float ma = blk_sum(a0 + a1 + a2, sh) * (1.f / 768.f);
  float mc = blk_sum(c0 + c1 + c2, sh) * (1.f / 768.f);
  float va = blk_sum((a0-ma)*(a0-ma) + (a1-ma)*(a1-ma) + (a2-ma)*(a2-ma), sh) * (1.f / 768.f);
  float vc = blk_sum((c0-mc)*(c0-mc) + (c1-mc)*(c1-mc) + (c2-mc)*(c2-mc), sh) * (1.f / 768.f);
  float ia = rsqrtf(va + 1e-6f), ic = rsqrtf(vc + 1e-6f);
  size_t ro = (size_t)row * Dd;
  size_t e1 = ((size_t)b * KVr + 1 + s) * Dd;
  size_t e2 = ((size_t)b * KVr + 1 + Ss + s) * Dd;
  float av[3] = {a0, a1, a2}, cv[3] = {c0, c1, c2};
  #pragma unroll
  for (int i = 0; i < 3; ++i) {
    int c = tid + i * 256;
    float an = (av[i] - ma) * ia * s1[c] + b1[c];
    float cn = (cv[i] - mc) * ic * s2[c] + b2[c];
    inputs[ro + c] = av[i] + cv[i];
    all_e[e1 + c]  = f2bf(an);
    all_e[e2 + c]  = f2bf(cn);
  }
}

// ---------------- split-K(2) combine + bias + residual + LN (wo path) ----------------
__global__ __launch_bounds__(256) void ln_comb2(
    const float* __restrict__ pk,
    const float* __restrict__ bias, const float* __restrict__ res,
    const float* __restrict__ sc, const float* __restrict__ bi,
    float* __restrict__ yf, short* __restrict__ yb)
{
  __shared__ float sh[4];
  const int row = blockIdx.x, tid = threadIdx.x;
  const size_t PS = (size_t)2048 * 768;
  size_t ro = (size_t)row * Dd;
  float vv[3];
  #pragma unroll
  for (int i = 0; i < 3; ++i) {
    int c = tid + i * 256;
    vv[i] = pk[ro + c] + pk[PS + ro + c] + bias[c] + res[ro + c];
  }
  float m = blk_sum(vv[0] + vv[1] + vv[2], sh) * (1.f / 768.f);
  float var = blk_sum((vv[0]-m)*(vv[0]-m) + (vv[1]-m)*(vv[1]-m) + (vv[2]-m)*(vv[2]-m), sh) * (1.f / 768.f);
  float inv = rsqrtf(var + 1e-6f);
  #pragma unroll
  for (int i = 0; i < 3; ++i) {
    int c = tid + i * 256;
    yf[ro + c] = vv[i];
    yb[ro + c] = f2bf((vv[i] - m) * inv * sc[c] + bi[c]);
  }
}

// ---------------- split-K(4) combine + LN + FiLM (standalone, r1) ----------------
__global__ __launch_bounds__(256) void ln_comb(
    const float* __restrict__ pk,
    const float* __restrict__ bias, const float* __restrict__ res,
    const float* __restrict__ sc, const float* __restrict__ bi,
    const float* __restrict__ film, float* __restrict__ yf, short* __restrict__ yb)
{
  __shared__ float sh[4];
  const int row = blockIdx.x, tid = threadIdx.x;
  const size_t PS = (size_t)2048 * 768;
  size_t ro = (size_t)row * Dd;
  float vv[3];
  #pragma unroll
  for (int i = 0; i < 3; ++i) {
    int c = tid + i * 256;
    float v = bias[c] + res[ro + c];
    #pragma unroll
    for (int s = 0; s < 4; ++s) v += pk[s * PS + ro + c];
    vv[i] = v;
  }
  float m = blk_sum(vv[0] + vv[1] + vv[2], sh) * (1.f / 768.f);
  float var = blk_sum((vv[0]-m)*(vv[0]-m) + (vv[1]-m)*(vv[1]-m) + (vv[2]-m)*(vv[2]-m), sh) * (1.f / 768.f);
  float inv = rsqrtf(var + 1e-6f);
  int bb = row >> 10;
  #pragma unroll
  for (int i = 0; i < 3; ++i) {
    int c = tid + i * 256;
    float o = (vv[i] - m) * inv * sc[c] + bi[c];
    o = film[(size_t)bb * 1536 + c] * o + film[(size_t)bb * 1536 + 768 + c];
    if (yf) yf[ro + c] = o;
    if (yb) yb[ro + c] = f2bf(o);
  }
}

// ---------------- merged: combine(ff) [0-2047] + convT2(r0) [2048-3199] ----------------
__global__ __launch_bounds__(256) void comb_convT2(
    const float* __restrict__ pk, const float* __restrict__ bias, const float* __restrict__ res,
    float* __restrict__ yf, short* __restrict__ yb,
    const float* __restrict__ W1, short* __restrict__ D1,
    const float* __restrict__ W2, short* __restrict__ D2)
{
  const int tid = threadIdx.x;
  if (blockIdx.x >= 2048) {
    __shared__ short T[64][72];
    const int id = blockIdx.x - 2048;
    const bool second = id >= 576;
    const int id576 = second ? (id - 576) : id;
    const int K = second ? 3072 : 768;
    const int N = second ? 768 : 3072;
    const int ntile = N >> 6;
    const float* W = second ? W2 : W1;
    short* Wt = second ? D2 : D1;
    const int bn = id576 % ntile, bk = id576 / ntile;
    const int k0 = bk * 64, n0 = bn * 64;
    #pragma unroll
    for (int i = 0; i < 4; ++i) {
      int jd = i * 256 + tid;
      int r = jd >> 4, c4 = (jd & 15) * 4;
      float4 w4 = *(const float4*)(W + (size_t)(k0 + r) * N + n0 + c4);
      T[c4 + 0][r] = f2bf(w4.x);
      T[c4 + 1][r] = f2bf(w4.y);
      T[c4 + 2][r] = f2bf(w4.z);
      T[c4 + 3][r] = f2bf(w4.w);
    }
    __syncthreads();
    #pragma unroll
    for (int i = 0; i < 4; ++i) {
      int jd = i * 256 + tid;
      int nn = jd >> 4, k4 = (jd & 15) * 4;
      short4v s = *(const short4v*)&T[nn][k4];
      *(short4v*)(Wt + (size_t)(n0 + nn) * K + k0 + k4) = s;
    }
    return;
  }
  const int row = blockIdx.x;
  const size_t PS = (size_t)2048 * 768;
  size_t ro = (size_t)row * Dd;
  #pragma unroll
  for (int i = 0; i < 3; ++i) {
    int c = tid + i * 256;
    float v = bias[c] + res[ro + c];
    #pragma unroll
    for (int s = 0; s < 4; ++s) v += pk[s * PS + ro + c];
    yf[ro + c] = v;
    yb[ro + c] = f2bf(v);
  }
}

// ---------------- merged: ln_comb(r0) [0-2047] + convT2(r1) [2048-3199] ----------------
__global__ __launch_bounds__(256) void lncomb_convT2(
    const float* __restrict__ pk, const float* __restrict__ bias, const float* __restrict__ res,
    const float* __restrict__ sc, const float* __restrict__ bi,
    const float* __restrict__ film, float* __restrict__ yf, short* __restrict__ yb,
    const float* __restrict__ W1, short* __restrict__ D1,
    const float* __restrict__ W2, short* __restrict__ D2)
{
  const int tid = threadIdx.x;
  if (blockIdx.x >= 2048) {
    __shared__ short T[64][72];
    const int id = blockIdx.x - 2048;
    const bool second = id >= 576;
    const int id576 = second ? (id - 576) : id;
    const int K = second ? 3072 : 768;
    const int N = second ? 768 : 3072;
    const int ntile = N >> 6;
    const float* W = second ? W2 : W1;
    short* Wt = second ? D2 : D1;
    const int bn = id576 % ntile, bk = id576 / ntile;
    const int k0 = bk * 64, n0 = bn * 64;
    #pragma unroll
    for (int i = 0; i < 4; ++i) {
      int jd = i * 256 + tid;
      int r = jd >> 4, c4 = (jd & 15) * 4;
      float4 w4 = *(const float4*)(W + (size_t)(k0 + r) * N + n0 + c4);
      T[c4 + 0][r] = f2bf(w4.x);
      T[c4 + 1][r] = f2bf(w4.y);
      T[c4 + 2][r] = f2bf(w4.z);
      T[c4 + 3][r] = f2bf(w4.w);
    }
    __syncthreads();
    #pragma unroll
    for (int i = 0; i < 4; ++i) {
      int jd = i * 256 + tid;
      int nn = jd >> 4, k4 = (jd & 15) * 4;
      short4v s = *(const short4v*)&T[nn][k4];
      *(short4v*)(Wt + (size_t)(n0 + nn) * K + k0 + k4) = s;
    }
    return;
  }
  __shared__ float sh[4];
  const int row = blockIdx.x;
  const size_t PS = (size_t)2048 * 768;
  size_t ro = (size_t)row * Dd;
  float vv[3];
  #pragma unroll
  for (int i = 0; i < 3; ++i) {
    int c = tid + i * 256;
    float v = bias[c] + res[ro + c];
    #pragma unroll
    for (int s = 0; s < 4; ++s) v += pk[s * PS + ro + c];
    vv[i] = v;
  }
  float m = blk_sum(vv[0] + vv[1] + vv[2], sh) * (1.f / 768.f);
  float var = blk_sum((vv[0]-m)*(vv[0]-m) + (vv[1]-m)*(vv[1]-m) + (vv[2]-m)*(vv[2]-m), sh) * (1.f / 768.f);
  float inv = rsqrtf(var + 1e-6f);
  int bb = row >> 10;
  #pragma unroll
  for (int i = 0; i < 3; ++i) {
    int c = tid + i * 256;
    float o = (vv[i] - m) * inv * sc[c] + bi[c];
    o = film[(size_t)bb * 1536 + c] * o + film[(size_t)bb * 1536 + 768 + c];
    yf[ro + c] = o;
    yb[ro + c] = f2bf(o);
  }
}

// ---------------- plain convT (out_w) and convT2 (ff) ----------------
__global__ __launch_bounds__(256) void convT(const float* __restrict__ W, short* __restrict__ Wt,
                                             int K, int N, int ntile)
{
  __shared__ short T[64][72];
  const int bn = blockIdx.x % ntile, bk = blockIdx.x / ntile;
  const int k0 = bk * 64, n0 = bn * 64, tid = threadIdx.x;
  #pragma unroll
  for (int i = 0; i < 4; ++i) {
    int id = i * 256 + tid;
    int r = id >> 4, c4 = (id & 15) * 4;
    float4 w4 = *(const float4*)(W + (size_t)(k0 + r) * N + n0 + c4);
    T[c4 + 0][r] = f2bf(w4.x);
    T[c4 + 1][r] = f2bf(w4.y);
    T[c4 + 2][r] = f2bf(w4.z);
    T[c4 + 3][r] = f2bf(w4.w);
  }
  __syncthreads();
  #pragma unroll
  for (int i = 0; i < 4; ++i) {
    int id = i * 256 + tid;
    int n = id >> 4, k4 = (id & 15) * 4;
    short4v s = *(const short4v*)&T[n][k4];
    *(short4v*)(Wt + (size_t)(n0 + n) * K + k0 + k4) = s;
  }
}

__global__ __launch_bounds__(256) void convT2(const float* __restrict__ W1, short* __restrict__ D1,
                                              const float* __restrict__ W2, short* __restrict__ D2)
{
  __shared__ short T[64][72];
  const int tid = threadIdx.x;
  const bool second = blockIdx.x >= 576;
  const int id576 = second ? (blockIdx.x - 576) : blockIdx.x;
  const int K = second ? 3072 : 768;
  const int N = second ? 768 : 3072;
  const int ntile = N >> 6;
  const float* W = second ? W2 : W1;
  short* Wt = second ? D2 : D1;
  const int bn = id576 % ntile, bk = id576 / ntile;
  const int k0 = bk * 64, n0 = bn * 64;
  #pragma unroll
  for (int i = 0; i < 4; ++i) {
    int id = i * 256 + tid;
    int r = id >> 4, c4 = (id & 15) * 4;
    float4 w4 = *(const float4*)(W + (size_t)(k0 + r) * N + n0 + c4);
    T[c4 + 0][r] = f2bf(w4.x);
    T[c4 + 1][r] = f2bf(w4.y);
    T[c4 + 2][r] = f2bf(w4.z);
    T[c4 + 3][r] = f2bf(w4.w);
  }
  __syncthreads();
  #pragma unroll
  for (int i = 0; i < 4; ++i) {
    int id = i * 256 + tid;
    int n = id >> 4, k4 = (id & 15) * 4;
    short4v s = *(const short4v*)&T[n][k4];
    *(short4v*)(Wt + (size_t)(n0 + n) * K + k0 + k4) = s;
  }
}

// ---------------- 128x128 bf16 GEMM, BK=32 dbuf, 4 blocks/CU ----------------
template<int ACT>
__global__ __launch_bounds__(256, 4) void gemm_bf(
    const short* __restrict__ A, const short* __restrict__ Bt,
    const float* __restrict__ bias, const float* __restrict__ res,
    float* __restrict__ C, short* __restrict__ Cbf, float* __restrict__ Cpart,
    int M, int N, int K, float scale, int mtiles, int ntiles, int ksplit)
{
  __shared__ short As[2][4096];
  __shared__ short Bs[2][4096];
  const int tid = threadIdx.x, lane = tid & 63, wv = tid >> 6;
  const int l15 = lane & 15, l4 = lane >> 4;

  const int nwg = gridDim.x;
  const int qc = nwg >> 3, rc = nwg & 7;
  const int xcd = blockIdx.x & 7, idx = blockIdx.x >> 3;
  const int wgid = (xcd < rc ? xcd * (qc + 1) : rc * (qc + 1) + (xcd - rc) * qc) + idx;
  const int by = wgid % mtiles;
  const int rest = wgid / mtiles;
  const int bx = rest % ntiles;
  const int sp = rest / ntiles;
  const int kper = K / ksplit;
  const int kbeg = sp * kper;
  const int NT = kper >> 5;

  const int m0 = by * 128, n0 = bx * 128;
  const int wm = (wv >> 1) * 64, wn = (wv & 1) * 64;

  const int srow = lane >> 2, schunk = lane & 3;
  const int scsw = (schunk ^ ((srow >> 1) & 3)) << 3;
  const short* sA = A + (size_t)(m0 + wv * 32 + srow) * K + kbeg + scsw;
  const short* sB = Bt + (size_t)(n0 + wv * 32 + srow) * K + kbeg + scsw;
  const int stBase = wv * 1024;
  const int frsw = (l4 ^ ((l15 >> 1) & 3)) << 3;

  f32x4 acc[4][4];
  const f32x4 zz = {0.f, 0.f, 0.f, 0.f};
  #pragma unroll
  for (int i = 0; i < 4; ++i)
    #pragma unroll
    for (int j = 0; j < 4; ++j) acc[i][j] = zz;

  GL16(sA, &As[0][stBase]);
  GL16(sA + (size_t)16 * K, &As[0][stBase + 512]);
  GL16(sB, &Bs[0][stBase]);
  GL16(sB + (size_t)16 * K, &Bs[0][stBase + 512]);

  int buf = 0;
  for (int t = 0; t < NT; ++t) {
    if (t + 1 < NT) {
      int k0 = (t + 1) << 5;
      GL16(sA + k0, &As[buf ^ 1][stBase]);
      GL16(sA + (size_t)16 * K + k0, &As[buf ^ 1][stBase + 512]);
      GL16(sB + k0, &Bs[buf ^ 1][stBase]);
      GL16(sB + (size_t)16 * K + k0, &Bs[buf ^ 1][stBase + 512]);
      asm volatile("s_waitcnt vmcnt(4)" ::: "memory");
    } else {
      asm volatile("s_waitcnt vmcnt(0)" ::: "memory");
    }
    __builtin_amdgcn_s_barrier();

    short8v af[4], bfv[4];
    #pragma unroll
    for (int mi = 0; mi < 4; ++mi)
      af[mi] = *(const short8v*)&As[buf][(wm + mi * 16 + l15) * 32 + frsw];
    #pragma unroll
    for (int ni = 0; ni < 4; ++ni)
      bfv[ni] = *(const short8v*)&Bs[buf][(wn + ni * 16 + l15) * 32 + frsw];
    __builtin_amdgcn_s_setprio(1);
    #pragma unroll
    for (int mi = 0; mi < 4; ++mi)
      #pragma unroll
      for (int ni = 0; ni < 4; ++ni)
        acc[mi][ni] = __builtin_amdgcn_mfma_f32_16x16x32_bf16(af[mi], bfv[ni], acc[mi][ni], 0, 0, 0);
    __builtin_amdgcn_s_setprio(0);
    if (t + 1 < NT) __builtin_amdgcn_s_barrier();
    buf ^= 1;
  }

  if (Cpart) {
    float* Cp = Cpart + (size_t)sp * M * N;
    #pragma unroll
    for (int mi = 0; mi < 4; ++mi)
      #pragma unroll
      for (int r = 0; r < 4; ++r) {
        int row = m0 + wm + mi * 16 + l4 * 4 + r;
        if (row >= M) continue;
        size_t rb = (size_t)row * N;
        #pragma unroll
        for (int ni = 0; ni < 4; ++ni)
          Cp[rb + n0 + wn + ni * 16 + l15] = acc[mi][ni][r];
      }
    return;
  }

  #pragma unroll
  for (int mi = 0; mi < 4; ++mi) {
    #pragma unroll
    for (int r = 0; r < 4; ++r) {
      int row = m0 + wm + mi * 16 + l4 * 4 + r;
      if (row >= M) continue;
      size_t rb = (size_t)row * N;
      #pragma unroll
      for (int ni = 0; ni < 4; ++ni) {
        int col = n0 + wn + ni * 16 + l15;
        float val = (acc[mi][ni][r] + bias[col]) * scale;
        if (ACT == 1) val = fmaxf(val, 0.f);
        if (ACT == 2) val = gelu_f(val);
        if (res) val += res[rb + col];
        if (C)   C[rb + col] = val;
        if (Cbf) Cbf[rb + col] = f2bf(val);
      }
    }
  }
}

// ---------------- 256x256 / 8-wave / BK=64 / 4-phase, 2 barriers/tile (vocab) ----------------
__global__ __launch_bounds__(512, 2) void gemm256(
    const short* __restrict__ A, const short* __restrict__ Bt,
    const float* __restrict__ bias, float* __restrict__ C,
    int M, int N, int K, int mtiles)
{
  __shared__ short As[2][16384];
  __shared__ short Bs[2][16384];
  const int tid = threadIdx.x, lane = tid & 63, wv = tid >> 6;
  const int l15 = lane & 15, l4 = lane >> 4;

  const int nwg = gridDim.x;
  const int qc = nwg >> 3, rc = nwg & 7;
  const int xcd = blockIdx.x & 7, idx = blockIdx.x >> 3;
  const int wgid = (xcd < rc ? xcd * (qc + 1) : rc * (qc + 1) + (xcd - rc) * qc) + idx;
  const int by = wgid % mtiles, bx = wgid / mtiles;
  const int m0 = by * 256, n0 = bx * 256;
  const int wm = (wv >> 2) * 128, wn = (wv & 3) * 64;

  const int srow = lane >> 2, schunk = lane & 3;
  const int scsw = (schunk ^ ((srow >> 1) & 3)) << 3;
  const short* sA = A + (size_t)(m0 + wv * 16 + srow) * K + scsw;
  const short* sB = Bt + (size_t)(n0 + wv * 16 + srow) * K + scsw;
  const int stBase = wv * 512;
  const int frsw = (l4 ^ ((l15 >> 1) & 3)) << 3;

  #define STG_A(b, kk, ko) do { \
    GL16(sA + (ko) + (kk) * 32,                  &As[b][(kk) * 8192 + stBase]); \
    GL16(sA + (size_t)128 * K + (ko) + (kk) * 32, &As[b][(kk) * 8192 + 4096 + stBase]); } while (0)
  #define STG_B(b, kk, ko) do { \
    GL16(sB + (ko) + (kk) * 32,                  &Bs[b][(kk) * 8192 + stBase]); \
    GL16(sB + (size_t)128 * K + (ko) + (kk) * 32, &Bs[b][(kk) * 8192 + 4096 + stBase]); } while (0)
  #define ARD(b, kk, row) (*(const short8v*)&As[b][(kk) * 8192 + (row) * 32 + frsw])
  #define BRD(b, kk, row) (*(const short8v*)&Bs[b][(kk) * 8192 + (row) * 32 + frsw])

  f32x4 acc[8][4];
  const f32x4 zz = {0.f, 0.f, 0.f, 0.f};
  #pragma unroll
  for (int i = 0; i < 8; ++i)
    #pragma unroll
    for (int j = 0; j < 4; ++j) acc[i][j] = zz;

  const int NT = K >> 6;

  STG_A(0, 0, 0); STG_B(0, 0, 0); STG_A(0, 1, 0); STG_B(0, 1, 0);
  asm volatile("s_waitcnt vmcnt(4)" ::: "memory");
  __builtin_amdgcn_s_barrier();

  int buf = 0;
  for (int t = 0; t < NT; ++t) {
    const bool pf = (t + 1 < NT);
    const int k1 = (t + 1) << 6;
    short8v af[4], bfv[4];

    #pragma unroll
    for (int mi = 0; mi < 4; ++mi) af[mi] = ARD(buf, 0, wm + mi * 16 + l15);
    #pragma unroll
    for (int ni = 0; ni < 4; ++ni) bfv[ni] = BRD(buf, 0, wn + ni * 16 + l15);
    if (pf) STG_A(buf ^ 1, 0, k1);
    asm volatile("s_waitcnt lgkmcnt(0)" ::: "memory");
    __builtin_amdgcn_sched_barrier(0);
    __builtin_amdgcn_s_setprio(1);
    #pragma unroll
    for (int mi = 0; mi < 4; ++mi)
      #pragma unroll
      for (int ni = 0; ni < 4; ++ni)
        acc[mi][ni] = __builtin_amdgcn_mfma_f32_16x16x32_bf16(af[mi], bfv[ni], acc[mi][ni], 0, 0, 0);
    __builtin_amdgcn_s_setprio(0);

    #pragma unroll
    for (int mi = 0; mi < 4; ++mi) af[mi] = ARD(buf, 0, wm + 64 + mi * 16 + l15);
    if (pf) STG_B(buf ^ 1, 0, k1);
    asm volatile("s_waitcnt lgkmcnt(0)" ::: "memory");
    __builtin_amdgcn_sched_barrier(0);
    __builtin_amdgcn_s_setprio(1);
    #pragma unroll
    for (int mi = 0; mi < 4; ++mi)
      #pragma unroll
      for (int ni = 0; ni < 4; ++ni)
        acc[4 + mi][ni] = __builtin_amdgcn_mfma_f32_16x16x32_bf16(af[mi], bfv[ni], acc[4 + mi][ni], 0, 0, 0);
    __builtin_amdgcn_s_setprio(0);
    if (pf) asm volatile("s_waitcnt vmcnt(4)" ::: "memory");
    else    asm volatile("s_waitcnt vmcnt(0)" ::: "memory");
    __builtin_amdgcn_s_barrier();

    #pragma unroll
    for (int mi = 0; mi < 4; ++mi) af[mi] = ARD(buf, 1, wm + mi * 16 + l15);
    #pragma unroll
    for (int ni = 0; ni < 4; ++ni) bfv[ni] = BRD(buf, 1, wn + ni * 16 + l15);
    if (pf) STG_A(buf ^ 1, 1, k1);
    asm volatile("s_waitcnt lgkmcnt(0)" ::: "memory");
    __builtin_amdgcn_sched_barrier(0);
    __builtin_amdgcn_s_setprio(1);
    #pragma unroll
    for (int mi = 0; mi < 4; ++mi)
      #pragma unroll
      for (int ni = 0; ni < 4; ++ni)
        acc[mi][ni] = __builtin_amdgcn_mfma_f32_16x16x32_bf16(af[mi], bfv[ni], acc[mi][ni], 0, 0, 0);
    __builtin_amdgcn_s_setprio(0);

    #pragma unroll
    for (int mi = 0; mi < 4; ++mi) af[mi] = ARD(buf, 1, wm + 64 + mi * 16 + l15);
    if (pf) STG_B(buf ^ 1, 1, k1);
    asm volatile("s_waitcnt lgkmcnt(0)" ::: "memory");
    __builtin_amdgcn_sched_barrier(0);
    __builtin_amdgcn_s_setprio(1);
    #pragma unroll
    for (int mi = 0; mi < 4; ++mi)
      #pragma unroll
      for (int ni = 0; ni < 4; ++ni)
        acc[4 + mi][ni] = __builtin_amdgcn_mfma_f32_16x16x32_bf16(af[mi], bfv[ni], acc[4 + mi][ni], 0, 0, 0);
    __builtin_amdgcn_s_setprio(0);
    if (pf) {
      asm volatile("s_waitcnt vmcnt(4)" ::: "memory");
      __builtin_amdgcn_s_barrier();
    }
    buf ^= 1;
  }

  #pragma unroll
  for (int mi = 0; mi < 8; ++mi) {
    #pragma unroll
    for (int r = 0; r < 4; ++r) {
      int row = m0 + wm + mi * 16 + l4 * 4 + r;
      size_t rb = (size_t)row * N;
      #pragma unroll
      for (int ni = 0; ni < 4; ++ni) {
        int col = n0 + wn + ni * 16 + l15;
        C[rb + col] = acc[mi][ni][r] + bias[col];
      }
    }
  }
  #undef STG_A
  #undef STG_B
  #undef ARD
  #undef BRD
}

// ---------------- flash attention, 4-chunk KV-split, q assembled in-kernel ----------------
__global__ __launch_bounds__(256) void attn_kernel(
    const short* __restrict__ kvq, const float* __restrict__ bq,
    float* __restrict__ Op0, float* __restrict__ Op1,
    float* __restrict__ Op2, float* __restrict__ Op3, float* __restrict__ ml)
{
  __shared__ short Kls[64][104];
  __shared__ short Vt[96][72];
  __shared__ short Pls[4][16][72];

  const int tid = threadIdx.x, lane = tid & 63, w = tid >> 6;
  const int l15 = lane & 15, l4 = lane >> 4;
  const int chunk = blockIdx.x >> 8;
  const int inner = blockIdx.x & 255;
  const int qt = inner & 15;
  const int bh = inner >> 4;
  const int h = bh & 7, b = bh >> 3;
  const int qb = qt * 64;
  const int qw = qb + w * 16;
  const float qsc = 0.1020620726159658f;   // 1/sqrt(96)

  short8v qf[3];
  {
    const short* p1 = kvq + ((size_t)b * KVr + 1 + qw + l15) * 2304 + h * HDh + l4 * 8;
    const short* p2 = p1 + (size_t)Ss * 2304;
    #pragma unroll
    for (int kk = 0; kk < 3; ++kk) {
      short8v a8 = *(const short8v*)(p1 + kk * 32);
      short8v b8 = *(const short8v*)(p2 + kk * 32);
      short8v tq;
      #pragma unroll
      for (int j = 0; j < 8; ++j)
        tq[j] = f2bf((bf2f(a8[j]) + bf2f(b8[j]) + bq[h * HDh + kk * 32 + l4 * 8 + j]) * qsc);
      qf[kk] = tq;
    }
  }

  const f32x4 zz = {0.f, 0.f, 0.f, 0.f};
  f32x4 Oa[6];
  #pragma unroll
  for (int fn = 0; fn < 6; ++fn) Oa[fn] = zz;
  float mrow[4], lrow[4];
  #pragma unroll
  for (int r = 0; r < 4; ++r) { mrow[r] = -3.0e38f; lrow[r] = 0.f; }

  const size_t kvbase = (size_t)b * KVr;

  for (int t = chunk; t < 33; t += 4) {
    int k0 = t * 64;
    bool l2r_vis = (k0 <= Ss) && (k0 - 1 <= qb + 63);
    int rmaxk = (k0 + 63 > 2 * Ss) ? 2 * Ss : (k0 + 63);
    bool r2l_vis = (k0 + 63 >= Ss + 1) && (rmaxk - (Ss + 1) >= qb);
    if (!(t == 0 || l2r_vis || r2l_vis)) continue;

    __syncthreads();
    #pragma unroll
    for (int i = 0; i < 3; ++i) {
      int id = i * 256 + tid;
      int row = id / 12, cc = (id % 12) * 8;
      int key = k0 + row;
      if (key > 2 * Ss) key = 2 * Ss;
      const short* kp = kvq + (kvbase + key) * 2304 + 768 + h * HDh + cc;
      short8v k8 = *(const short8v*)kp;
      *(short8v*)&Kls[row][cc] = k8;
      short8v v8 = *(const short8v*)(kp + 768);
      #pragma unroll
      for (int j = 0; j < 8; ++j) Vt[cc + j][row] = v8[j];
    }
    __syncthreads();

    f32x4 sc[4];
    #pragma unroll
    for (int nt = 0; nt < 4; ++nt) {
      f32x4 d = zz;
      #pragma unroll
      for (int kk = 0; kk < 3; ++kk) {
        short8v kf = *(const short8v*)&Kls[nt * 16 + l15][kk * 32 + l4 * 8];
        d = __builtin_amdgcn_mfma_f32_16x16x32_bf16(qf[kk], kf, d, 0, 0, 0);
      }
      sc[nt] = d;
    }
    float tmax[4] = {-3.0e38f, -3.0e38f, -3.0e38f, -3.0e38f};
    #pragma unroll
    for (int nt = 0; nt < 4; ++nt)
      #pragma unroll
      for (int r = 0; r < 4; ++r) {
        int qg = qw + l4 * 4 + r;
        int j = k0 + nt * 16 + l15;
        bool vis = (j == 0) ||
                   (j >= 1 && j <= Ss && (j - 1) <= qg) ||
                   (j >= Ss + 1 && j <= 2 * Ss && (j - (Ss + 1)) >= qg);
        if (!vis) sc[nt][r] = -3.0e38f;
        tmax[r] = fmaxf(tmax[r], sc[nt][r]);
      }
    #pragma unroll
    for (int r = 0; r < 4; ++r) {
      #pragma unroll
      for (int off = 8; off >= 1; off >>= 1) tmax[r] = fmaxf(tmax[r], __shfl_xor(tmax[r], off));
    }
    float scl[4];
    #pragma unroll
    for (int r = 0; r < 4; ++r) {
      float mnew = fmaxf(mrow[r], tmax[r]);
      scl[r] = __expf(mrow[r] - mnew);
      mrow[r] = mnew;
    }
    #pragma unroll
    for (int fn = 0; fn < 6; ++fn)
      #pragma unroll
      for (int r = 0; r < 4; ++r) Oa[fn][r] *= scl[r];
    float lad[4] = {0.f, 0.f, 0.f, 0.f};
    #pragma unroll
    for (int nt = 0; nt < 4; ++nt)
      #pragma unroll
      for (int r = 0; r < 4; ++r) {
        float p = __expf(sc[nt][r] - mrow[r]);
        lad[r] += p;
        Pls[w][l4 * 4 + r][nt * 16 + l15] = f2bf(p);
      }
    #pragma unroll
    for (int r = 0; r < 4; ++r) {
      #pragma unroll
      for (int off = 8; off >= 1; off >>= 1) lad[r] += __shfl_xor(lad[r], off);
      lrow[r] = lrow[r] * scl[r] + lad[r];
    }
    __syncthreads();

    short8v pf[2];
    #pragma unroll
    for (int kk = 0; kk < 2; ++kk) pf[kk] = *(const short8v*)&Pls[w][l15][kk * 32 + l4 * 8];
    #pragma unroll
    for (int fn = 0; fn < 6; ++fn) {
      #pragma unroll
      for (int kk = 0; kk < 2; ++kk) {
        short8v vf = *(const short8v*)&Vt[fn * 16 + l15][kk * 32 + l4 * 8];
        Oa[fn] = __builtin_amdgcn_mfma_f32_16x16x32_bf16(pf[kk], vf, Oa[fn], 0, 0, 0);
      }
    }
  }

  float* Op = (chunk == 0) ? Op0 : (chunk == 1) ? Op1 : (chunk == 2) ? Op2 : Op3;
  #pragma unroll
  for (int fn = 0; fn < 6; ++fn)
    #pragma unroll
    for (int r = 0; r < 4; ++r) {
      int row = qw + l4 * 4 + r;
      int col = h * HDh + fn * 16 + l15;
      Op[((size_t)(b * Ss + row)) * Dd + col] = Oa[fn][r];
    }
  if (l15 == 0) {
    #pragma unroll
    for (int r = 0; r < 4; ++r) {
      int row = qw + l4 * 4 + r;
      size_t ix = (size_t)chunk * 32768 + (((size_t)(b * 8 + h) * 1024 + row) * 2);
      ml[ix] = mrow[r];
      ml[ix + 1] = lrow[r];
    }
  }
}

// online-softmax merge of the 4 KV chunks -> attn_bf
__global__ __launch_bounds__(256) void attn_merge(
    const float* __restrict__ Op0, const float* __restrict__ Op1,
    const float* __restrict__ Op2, const float* __restrict__ Op3,
    const float* __restrict__ ml, short* __restrict__ o)
{
  const int row = blockIdx.x, tid = threadIdx.x;
  const int b = row >> 10, s = row & 1023;
  size_t ro = (size_t)row * Dd;
  #pragma unroll
  for (int i = 0; i < 3; ++i) {
    int c = tid + i * 256;
    int h = c / HDh;
    size_t ix = ((size_t)(b * 8 + h) * 1024 + s) * 2;
    float m0 = ml[ix], l0 = ml[ix + 1];
    float m1 = ml[32768 + ix], l1 = ml[32768 + ix + 1];
    float m2 = ml[65536 + ix], l2 = ml[65536 + ix + 1];
    float m3 = ml[98304 + ix], l3 = ml[98304 + ix + 1];
    float mm = fmaxf(fmaxf(m0, m1), fmaxf(m2, m3));
    float s0 = __expf(m0 - mm), s1 = __expf(m1 - mm);
    float s2 = __expf(m2 - mm), s3 = __expf(m3 - mm);
    float denom = s0 * l0 + s1 * l1 + s2 * l2 + s3 * l3;
    float val = s0 * Op0[ro + c] + s1 * Op1[ro + c] + s2 * Op2[ro + c] + s3 * Op3[ro + c];
    o[ro + c] = f2bf(val / denom);
  }
}

// ---------------- launch helpers ----------------
static void gemm_launch(int act, const short* A, const short* Bt, const float* bias,
                        const float* res, float* C, short* Cbf, float* Cpart,
                        int M, int N, int K, float scale, int ksplit, hipStream_t s)
{
  int mt = (M + 127) >> 7, nt = N >> 7;
  dim3 grid(mt * nt * ksplit), blk(256);
  if (act == 1)      gemm_bf<1><<<grid, blk, 0, s>>>(A, Bt, bias, res, C, Cbf, Cpart, M, N, K, scale, mt, nt, ksplit);
  else if (act == 2) gemm_bf<2><<<grid, blk, 0, s>>>(A, Bt, bias, res, C, Cbf, Cpart, M, N, K, scale, mt, nt, ksplit);
  else               gemm_bf<0><<<grid, blk, 0, s>>>(A, Bt, bias, res, C, Cbf, Cpart, M, N, K, scale, mt, nt, ksplit);
}

extern "C" void kernel_launch(void* const* d_in, const int* in_sizes, int n_in,
                              void* d_out, int out_size, void* d_ws, size_t ws_size,
                              hipStream_t stream)
{
  (void)in_sizes; (void)n_in; (void)out_size; (void)ws_size;
  const float* l2r      = (const float*)d_in[0];
  const float* r2l      = (const float*)d_in[1];
  const float* temb     = (const float*)d_in[2];
  const float* ln_l2r_s = (const float*)d_in[3];
  const float* ln_l2r_b = (const float*)d_in[4];
  const float* ln_r2l_s = (const float*)d_in[5];
  const float* ln_r2l_b = (const float*)d_in[6];
  const float* Wq = (const float*)d_in[7];
  const float* bq = (const float*)d_in[8];
  const float* Wk = (const float*)d_in[9];
  const float* bk = (const float*)d_in[10];
  const float* Wv = (const float*)d_in[11];
  const float* bv = (const float*)d_in[12];
  const float* Wo = (const float*)d_in[13];
  const float* bo = (const float*)d_in[14];
  const float* ff_ln_s = (const float*)d_in[15];
  const float* ff_ln_b = (const float*)d_in[16];
  const float* ff_w1 = (const float*)d_in[17];
  const float* ff_b1 = (const float*)d_in[18];
  const float* ff_w2 = (const float*)d_in[19];
  const float* ff_b2 = (const float*)d_in[20];
  const float* tm_w1 = (const float*)d_in[21];
  const float* tm_b1 = (const float*)d_in[22];
  const float* tm_w2 = (const float*)d_in[23];
  const float* tm_b2 = (const float*)d_in[24];
  const float* film_w = (const float*)d_in[25];
  const float* film_b = (const float*)d_in[26];
  const float* r_w1 = (const float*)d_in[27];
  const float* r_b1 = (const float*)d_in[28];
  const float* r_w2 = (const float*)d_in[29];
  const float* r_b2 = (const float*)d_in[30];
  const float* r_ln_s = (const float*)d_in[31];
  const float* r_ln_b = (const float*)d_in[32];
  const float* out_w = (const float*)d_in[33];
  const float* out_b = (const float*)d_in[34];

  uint8_t* base = (uint8_t*)d_ws;
  // layout identical to round 13 (liveness-verified)
  short* alle_bf = (short*)(base + 3145728);
  short* kvq     = (short*)(base + 9440256);    // ends 28,323,840
  short* attn_bf = (short*)(base + 12585984);
  float* inputs  = (float*)(base + 28323840);
  float* xbuf    = (float*)(base + 34615296);
  short* xn_bf   = (short*)(base + 40906752);
  short* big_bf  = (short*)(base + 44052480);
  float* x2f     = (float*)(base + 56635392);
  short* x2bf    = (short*)(base + 62926848);
  float* x3f     = (float*)(base + 66072576);
  short* x3bf    = (short*)(base + 72364032);
  short* x4bf    = (short*)(base + 75509760);
  short* wslot   = (short*)(base + 78655488);
  uint8_t* sm    = base + 83374080;
  float* f0    = (float*)(sm + 0);
  float* f1    = (float*)(sm + 12288);
  float* kvbia = (float*)(sm + 24576);
  short* w2slot = (short*)inputs;
  float* part2a = (float*)(base + 44052480);
  float* part2b = (float*)(base + 44052480 + 1572864);
  float* part2c = (float*)(base + 44052480 + 3145728);
  float* Op0 = (float*)(base + 3145728);
  float* Op1 = xbuf;
  float* Op2 = (float*)(base + 44052480);
  float* Op3 = (float*)(base + 50343936);
  float* mlb = (float*)(base + 56635392);
  float* wopart = (float*)(base + 44052480);
  float* partK = (float*)(base + 0);
  short* outwT = (short*)(base + 0);

  dim3 blk(256);

  // 1-3. t-path: thin1 -> thin1p(gelu+tm_w2) -> film1p (film2 folded into prep_conv)
  thin1<<<dim3(12 * 64), blk, 0, stream>>>(temb, tm_w1, part2a, 768, 3072, 12, 64);
  thin1p<<<dim3(12 * 64), blk, 0, stream>>>(part2a, tm_b1, tm_w2, part2b);
  film1p<<<dim3(12 * 64), blk, 0, stream>>>(part2b, tm_b2, film_w, part2c);

  // 4. prep + QKVO weight convert + bias concat + film2
  prep_conv<<<dim3(2639), blk, 0, stream>>>(l2r, r2l, temb, ln_l2r_s, ln_l2r_b, ln_r2l_s, ln_r2l_b,
                                            inputs, alle_bf, Wq, Wk, Wv, Wo, bk, bv, wslot, kvbia,
                                            part2c, film_b, f0, f1);

  // 5. fused QKV projection: E[4098,768] @ [Wq|Wk|Wv] -> kvq[4098,2304] bf16
  gemm_launch(0, alle_bf, wslot, kvbia, nullptr, nullptr, kvq, nullptr, 4098, 2304, 768, 1.f, 1, stream);

  // 6-7. attention (q assembled in-kernel), 4 KV chunks + merge
  attn_kernel<<<dim3(1024), blk, 0, stream>>>(kvq, bq, Op0, Op1, Op2, Op3, mlb);
  attn_merge<<<dim3(2048), blk, 0, stream>>>(Op0, Op1, Op2, Op3, mlb, attn_bf);

  // 8-9. Wo projection split-K(2) + fused combine/residual/LN
  gemm_launch(0, attn_bf, wslot + (size_t)3 * 768 * 768, bo, nullptr, nullptr, nullptr, wopart, 2048, 768, 768, 1.f, 2, stream);
  ln_comb2<<<dim3(2048), blk, 0, stream>>>(wopart, bo, inputs, ff_ln_s, ff_ln_b, xbuf, xn_bf);

  // 10-12. ff block
  convT2<<<dim3(1152), blk, 0, stream>>>(ff_w1, wslot, ff_w2, w2slot);
  gemm_launch(1, xn_bf, wslot, ff_b1, nullptr, nullptr, big_bf, nullptr, 2048, 3072, 768, 1.f, 1, stream);
  gemm_launch(0, big_bf, w2slot, nullptr, nullptr, nullptr, nullptr, partK, 2048, 768, 3072, 1.f, 4, stream);

  // 13. combine(ff) + convT2(r0) merged
  comb_convT2<<<dim3(3200), blk, 0, stream>>>(partK, ff_b2, xbuf, x2f, x2bf,
                                              r_w1, wslot, r_w2, w2slot);

  // 14-15. residual block 0 GEMMs
  gemm_launch(2, x2bf, wslot, r_b1, nullptr, nullptr, big_bf, nullptr, 2048, 3072, 768, 1.f, 1, stream);
  gemm_launch(0, big_bf, w2slot, nullptr, nullptr, nullptr, nullptr, partK, 2048, 768, 3072, 1.f, 4, stream);

  // 16. ln_comb(r0) + convT2(r1) merged
  lncomb_convT2<<<dim3(3200), blk, 0, stream>>>(partK, r_b2, x2f, r_ln_s, r_ln_b, f0, x3f, x3bf,
                                                r_w1 + (size_t)768 * 3072, wslot,
                                                r_w2 + (size_t)3072 * 768, w2slot);

  // 17-18. residual block 1 GEMMs
  gemm_launch(2, x3bf, wslot, r_b1 + 3072, nullptr, nullptr, big_bf, nullptr, 2048, 3072, 768, 1.f, 1, stream);
  gemm_launch(0, big_bf, w2slot, nullptr, nullptr, nullptr, nullptr, partK, 2048, 768, 3072, 1.f, 4, stream);

  // 19. ln_comb(r1)
  ln_comb<<<dim3(2048), blk, 0, stream>>>(partK, r_b2 + 768, x3f, r_ln_s + 768, r_ln_b + 768, f1, nullptr, x4bf);

  // 20-21. vocab projection
  convT<<<dim3(6000), blk, 0, stream>>>(out_w, outwT, 768, 32000, 500);
  gemm256<<<dim3(8 * 125), dim3(512), 0, stream>>>(x4bf, outwT, out_b, (float*)d_out,
                                                   2048, 32000, 768, 8);
}

// Round 16
// 520.971 us; speedup vs baseline: 1.4380x; 1.0154x over previous
//
#include <hip/hip_runtime.h>
#include <cstdint>
#include <cstddef>

#define Bb 2
#define Ss 1024
#define Dd 768
#define Hh 8
#define HDh 96
#define Mm 3072
#define Vv 32000
#define KVr 2049   // 2S+1

typedef __attribute__((ext_vector_type(8))) short short8v;
typedef __attribute__((ext_vector_type(4))) short short4v;
typedef __attribute__((ext_vector_type(4))) float f32x4;

#define GL16(gp, lp) __builtin_amdgcn_global_load_lds( \
    (const __attribute__((address_space(1))) void*)(gp), \
    (__attribute__((address_space(3))) void*)(lp), 16, 0, 0)

#define NTL(p) __builtin_nontemporal_load(p)
#define NTS(v, p) __builtin_nontemporal_store(v, p)

static __device__ __forceinline__ short f2bf(float f) {
  union { float f; unsigned u; } x; x.f = f;
  unsigned r = (x.u + 0x7FFFu + ((x.u >> 16) & 1u)) >> 16;  // RNE
  return (short)(r & 0xFFFFu);
}

static __device__ __forceinline__ float bf2f(short s) {
  union { unsigned u; float f; } x; x.u = ((unsigned)(unsigned short)s) << 16;
  return x.f;
}

static __device__ __forceinline__ float gelu_f(float v) {
  float u = 0.7978845608028654f * (v + 0.044715f * v * v * v);
  float au = fabsf(u);
  float e = __expf(2.f * au);
  float t = 1.f - 2.f / (e + 1.f);     // tanh(|u|), safe at inf
  return 0.5f * v * (1.f + copysignf(t, u));
}

static __device__ __forceinline__ float blk_sum(float val, float* sh) {
  #pragma unroll
  for (int off = 32; off >= 1; off >>= 1) val += __shfl_xor(val, off);
  __syncthreads();
  if ((threadIdx.x & 63) == 0) sh[threadIdx.x >> 6] = val;
  __syncthreads();
  return sh[0] + sh[1] + sh[2] + sh[3];
}

// ---------------- thin (M=2) GEMM stage 1 ----------------
__global__ __launch_bounds__(256) void thin1(const float* __restrict__ A, const float* __restrict__ W,
                                             float* __restrict__ part, int K, int N, int nblk, int splits)
{
  __shared__ float a0s[64], a1s[64];
  const int nb = blockIdx.x % nblk, ks = blockIdx.x / nblk;
  const int kl = K / splits, kbeg = ks * kl;
  const int tid = threadIdx.x;
  for (int k = tid; k < kl; k += 256) { a0s[k] = A[kbeg + k]; a1s[k] = A[K + kbeg + k]; }
  __syncthreads();
  const int n = nb * 256 + tid;
  float acc0 = 0.f, acc1 = 0.f;
  for (int k = 0; k < kl; ++k) {
    float w = W[(size_t)(kbeg + k) * N + n];
    acc0 = fmaf(a0s[k], w, acc0);
    acc1 = fmaf(a1s[k], w, acc1);
  }
  part[(size_t)ks * 2 * N + n] = acc0;
  part[(size_t)ks * 2 * N + N + n] = acc1;
}

// thin GEMM stage 2: A rebuilt from previous partials (+bias, gelu), K=3072, N=3072
__global__ __launch_bounds__(256) void thin1p(
    const float* __restrict__ pin, const float* __restrict__ bin,
    const float* __restrict__ W, float* __restrict__ part)
{
  __shared__ float a0s[48], a1s[48];
  const int nb = blockIdx.x % 12, ks = blockIdx.x / 12;
  const int kbeg = ks * 48, tid = threadIdx.x;
  for (int j = tid; j < 96; j += 256) {
    int row = j / 48, k = j % 48;
    float v = bin[kbeg + k];
    for (int s = 0; s < 64; ++s) v += pin[(size_t)s * 6144 + (size_t)row * 3072 + kbeg + k];
    v = gelu_f(v);
    if (row) a1s[k] = v; else a0s[k] = v;
  }
  __syncthreads();
  const int n = nb * 256 + tid;
  float acc0 = 0.f, acc1 = 0.f;
  for (int k = 0; k < 48; ++k) {
    float w = W[(size_t)(kbeg + k) * 3072 + n];
    acc0 = fmaf(a0s[k], w, acc0);
    acc1 = fmaf(a1s[k], w, acc1);
  }
  part[(size_t)ks * 6144 + n] = acc0;
  part[(size_t)ks * 6144 + 3072 + n] = acc1;
}

// FiLM pair GEMM: A rebuilt from tm_w2 partials (+tm_b2, no act)
__global__ __launch_bounds__(256) void film1p(
    const float* __restrict__ pin, const float* __restrict__ bin,
    const float* __restrict__ W, float* __restrict__ part)
{
  __shared__ float a0s[48], a1s[48];
  const int nb = blockIdx.x % 12, ks = blockIdx.x / 12;
  const int kbeg = ks * 48, tid = threadIdx.x;
  for (int j = tid; j < 96; j += 256) {
    int row = j / 48, k = j % 48;
    float v = bin[kbeg + k];
    for (int s = 0; s < 64; ++s) v += pin[(size_t)s * 6144 + (size_t)row * 3072 + kbeg + k];
    if (row) a1s[k] = v; else a0s[k] = v;
  }
  __syncthreads();
  const int n = nb * 256 + tid;
  const int col = (n >= 1536) ? (n - 1536) : n;
  const float* Wp = W + ((n < 1536) ? (size_t)0 : (size_t)3072 * 1536)
                      + (size_t)kbeg * 1536 + col;
  float acc0 = 0.f, acc1 = 0.f;
  for (int k = 0; k < 48; ++k) {
    float w = Wp[(size_t)k * 1536];
    acc0 = fmaf(a0s[k], w, acc0);
    acc1 = fmaf(a1s[k], w, acc1);
  }
  part[(size_t)ks * 6144 + n] = acc0;
  part[(size_t)ks * 6144 + 3072 + n] = acc1;
}

// ---------------- prep (0-2049) + QKVO convert/bias (2050-2626) + film2 (2627-2638) ----------------
__global__ __launch_bounds__(256) void prep_conv(
    const float* __restrict__ l2r, const float* __restrict__ r2l,
    const float* __restrict__ temb,
    const float* __restrict__ s1, const float* __restrict__ b1,
    const float* __restrict__ s2, const float* __restrict__ b2,
    float* __restrict__ inputs, short* __restrict__ all_e,
    const float* __restrict__ W0, const float* __restrict__ W1,
    const float* __restrict__ W2, const float* __restrict__ W3,
    const float* __restrict__ bk, const float* __restrict__ bv,
    short* __restrict__ Wt, float* __restrict__ kvb,
    const float* __restrict__ part2c, const float* __restrict__ fb,
    float* __restrict__ f0, float* __restrict__ f1)
{
  __shared__ float sh[4];
  __shared__ short T[64][72];
  const int tid = threadIdx.x;

  if (blockIdx.x >= 2627) {   // film2 reduction (12 blocks)
    const int n = (blockIdx.x - 2627) * 256 + tid;
    float a0 = fb[n], a1 = a0;
    for (int s = 0; s < 64; ++s) {
      a0 += part2c[(size_t)s * 6144 + n];
      a1 += part2c[(size_t)s * 6144 + 3072 + n];
    }
    float* dst = (n < 1536) ? f0 : f1;
    const int c = (n >= 1536) ? (n - 1536) : n;
    dst[c] = a0;
    dst[1536 + c] = a1;
    return;
  }

  if (blockIdx.x >= 2050) {
    const int cb = blockIdx.x - 2050;   // 0..576
    if (cb == 576) {   // bias [0 | bk | bv], 2304 wide
      #pragma unroll
      for (int i = 0; i < 9; ++i) {
        int c = i * 256 + tid;
        if (c < 2304) kvb[c] = (c < 768) ? 0.f : (c < 1536 ? bk[c - 768] : bv[c - 1536]);
      }
      return;
    }
    const int wsel = cb / 144, rem = cb % 144;
    const float* W = wsel == 0 ? W0 : wsel == 1 ? W1 : wsel == 2 ? W2 : W3;
    short* dst = Wt + (size_t)wsel * 768 * 768;
    const int bn = rem % 12, bk2 = rem / 12;
    const int k0 = bk2 * 64, n0 = bn * 64;
    #pragma unroll
    for (int i = 0; i < 4; ++i) {
      int id = i * 256 + tid;
      int r = id >> 4, c4 = (id & 15) * 4;
      float4 w4 = *(const float4*)(W + (size_t)(k0 + r) * 768 + n0 + c4);
      T[c4 + 0][r] = f2bf(w4.x);
      T[c4 + 1][r] = f2bf(w4.y);
      T[c4 + 2][r] = f2bf(w4.z);
      T[c4 + 3][r] = f2bf(w4.w);
    }
    __syncthreads();
    #pragma unroll
    for (int i = 0; i < 4; ++i) {
      int id = i * 256 + tid;
      int nn = id >> 4, k4 = (id & 15) * 4;
      short4v s = *(const short4v*)&T[nn][k4];
      *(short4v*)(dst + (size_t)(n0 + nn) * 768 + k0 + k4) = s;
    }
    return;
  }

  if (blockIdx.x >= 2048) {   // temb rows of all_e
    int b = blockIdx.x - 2048;
    #pragma unroll
    for (int i = 0; i < 3; ++i)
      all_e[(size_t)b * KVr * Dd + tid + i * 256] = f2bf(temb[(size_t)b * Dd + tid + i * 256]);
    return;
  }
  const int row = blockIdx.x;
  const int b = row >> 10, s = row & 1023;
  const float* ap = l2r + (size_t)row * Dd;
  const float* cp = r2l + (size_t)row * Dd;
  float a0 = ap[tid], a1 = ap[tid + 256], a2 = ap[tid + 512];
  float c0 = cp[tid], c1 = cp[tid + 256], c2 = cp[tid + 512];
  float ma = blk_sum(a0 + a1 + a2, sh) * (1.f / 768.f);
  float mc = blk_sum(c0 + c1 + c2, sh) * (1.f / 768.f);
  float va = blk_sum((a0-ma)*(a0-ma) + (a1-ma)*(a1-ma) + (a2-ma)*(a2-ma), sh) * (1.f / 768.f);
  float vc = blk_sum((c0-mc)*(c0-mc) + (c1-mc)*(c1-mc) + (c2-mc)*(c2-mc), sh) * (1.f / 768.f);
  float ia = rsqrtf(va + 1e-6f), ic = rsqrtf(vc + 1e-6f);
  size_t ro = (size_t)row * Dd;
  size_t e1 = ((size_t)b * KVr + 1 + s) * Dd;
  size_t e2 = ((size_t)b * KVr + 1 + Ss + s) * Dd;
  float av[3] = {a0, a1, a2}, cv[3] = {c0, c1, c2};
  #pragma unroll
  for (int i = 0; i < 3; ++i) {
    int c = tid + i * 256;
    float an = (av[i] - ma) * ia * s1[c] + b1[c];
    float cn = (cv[i] - mc) * ic * s2[c] + b2[c];
    inputs[ro + c] = av[i] + cv[i];
    all_e[e1 + c]  = f2bf(an);
    all_e[e2 + c]  = f2bf(cn);
  }
}

// ---------------- split-K(2) combine + bias + residual + LN (wo path) ----------------
__global__ __launch_bounds__(256) void ln_comb2(
    const float* __restrict__ pk,
    const float* __restrict__ bias, const float* __restrict__ res,
    const float* __restrict__ sc, const float* __restrict__ bi,
    float* __restrict__ yf, short* __restrict__ yb)
{
  __shared__ float sh[4];
  const int row = blockIdx.x, tid = threadIdx.x;
  const size_t PS = (size_t)2048 * 768;
  size_t ro = (size_t)row * Dd;
  float vv[3];
  #pragma unroll
  for (int i = 0; i < 3; ++i) {
    int c = tid + i * 256;
    vv[i] = NTL(&pk[ro + c]) + NTL(&pk[PS + ro + c]) + bias[c] + res[ro + c];
  }
  float m = blk_sum(vv[0] + vv[1] + vv[2], sh) * (1.f / 768.f);
  float var = blk_sum((vv[0]-m)*(vv[0]-m) + (vv[1]-m)*(vv[1]-m) + (vv[2]-m)*(vv[2]-m), sh) * (1.f / 768.f);
  float inv = rsqrtf(var + 1e-6f);
  #pragma unroll
  for (int i = 0; i < 3; ++i) {
    int c = tid + i * 256;
    yf[ro + c] = vv[i];
    yb[ro + c] = f2bf((vv[i] - m) * inv * sc[c] + bi[c]);
  }
}

// ---------------- split-K(4) combine + LN + FiLM (standalone, r1) ----------------
__global__ __launch_bounds__(256) void ln_comb(
    const float* __restrict__ pk,
    const float* __restrict__ bias, const float* __restrict__ res,
    const float* __restrict__ sc, const float* __restrict__ bi,
    const float* __restrict__ film, float* __restrict__ yf, short* __restrict__ yb)
{
  __shared__ float sh[4];
  const int row = blockIdx.x, tid = threadIdx.x;
  const size_t PS = (size_t)2048 * 768;
  size_t ro = (size_t)row * Dd;
  float vv[3];
  #pragma unroll
  for (int i = 0; i < 3; ++i) {
    int c = tid + i * 256;
    float v = bias[c] + res[ro + c];
    #pragma unroll
    for (int s = 0; s < 4; ++s) v += NTL(&pk[s * PS + ro + c]);
    vv[i] = v;
  }
  float m = blk_sum(vv[0] + vv[1] + vv[2], sh) * (1.f / 768.f);
  float var = blk_sum((vv[0]-m)*(vv[0]-m) + (vv[1]-m)*(vv[1]-m) + (vv[2]-m)*(vv[2]-m), sh) * (1.f / 768.f);
  float inv = rsqrtf(var + 1e-6f);
  int bb = row >> 10;
  #pragma unroll
  for (int i = 0; i < 3; ++i) {
    int c = tid + i * 256;
    float o = (vv[i] - m) * inv * sc[c] + bi[c];
    o = film[(size_t)bb * 1536 + c] * o + film[(size_t)bb * 1536 + 768 + c];
    if (yf) yf[ro + c] = o;
    if (yb) yb[ro + c] = f2bf(o);
  }
}

// ---------------- merged: combine(ff) [0-2047] + convT2(r0) [2048-3199] ----------------
__global__ __launch_bounds__(256) void comb_convT2(
    const float* __restrict__ pk, const float* __restrict__ bias, const float* __restrict__ res,
    float* __restrict__ yf, short* __restrict__ yb,
    const float* __restrict__ W1, short* __restrict__ D1,
    const float* __restrict__ W2, short* __restrict__ D2)
{
  const int tid = threadIdx.x;
  if (blockIdx.x >= 2048) {
    __shared__ short T[64][72];
    const int id = blockIdx.x - 2048;
    const bool second = id >= 576;
    const int id576 = second ? (id - 576) : id;
    const int K = second ? 3072 : 768;
    const int N = second ? 768 : 3072;
    const int ntile = N >> 6;
    const float* W = second ? W2 : W1;
    short* Wt = second ? D2 : D1;
    const int bn = id576 % ntile, bk = id576 / ntile;
    const int k0 = bk * 64, n0 = bn * 64;
    #pragma unroll
    for (int i = 0; i < 4; ++i) {
      int jd = i * 256 + tid;
      int r = jd >> 4, c4 = (jd & 15) * 4;
      float4 w4 = *(const float4*)(W + (size_t)(k0 + r) * N + n0 + c4);
      T[c4 + 0][r] = f2bf(w4.x);
      T[c4 + 1][r] = f2bf(w4.y);
      T[c4 + 2][r] = f2bf(w4.z);
      T[c4 + 3][r] = f2bf(w4.w);
    }
    __syncthreads();
    #pragma unroll
    for (int i = 0; i < 4; ++i) {
      int jd = i * 256 + tid;
      int nn = jd >> 4, k4 = (jd & 15) * 4;
      short4v s = *(const short4v*)&T[nn][k4];
      *(short4v*)(Wt + (size_t)(n0 + nn) * K + k0 + k4) = s;
    }
    return;
  }
  const int row = blockIdx.x;
  const size_t PS = (size_t)2048 * 768;
  size_t ro = (size_t)row * Dd;
  #pragma unroll
  for (int i = 0; i < 3; ++i) {
    int c = tid + i * 256;
    float v = bias[c] + res[ro + c];
    #pragma unroll
    for (int s = 0; s < 4; ++s) v += NTL(&pk[s * PS + ro + c]);
    yf[ro + c] = v;
    yb[ro + c] = f2bf(v);
  }
}

// ---------------- merged: ln_comb(r0) [0-2047] + convT2(r1) [2048-3199] ----------------
__global__ __launch_bounds__(256) void lncomb_convT2(
    const float* __restrict__ pk, const float* __restrict__ bias, const float* __restrict__ res,
    const float* __restrict__ sc, const float* __restrict__ bi,
    const float* __restrict__ film, float* __restrict__ yf, short* __restrict__ yb,
    const float* __restrict__ W1, short* __restrict__ D1,
    const float* __restrict__ W2, short* __restrict__ D2)
{
  const int tid = threadIdx.x;
  if (blockIdx.x >= 2048) {
    __shared__ short T[64][72];
    const int id = blockIdx.x - 2048;
    const bool second = id >= 576;
    const int id576 = second ? (id - 576) : id;
    const int K = second ? 3072 : 768;
    const int N = second ? 768 : 3072;
    const int ntile = N >> 6;
    const float* W = second ? W2 : W1;
    short* Wt = second ? D2 : D1;
    const int bn = id576 % ntile, bk = id576 / ntile;
    const int k0 = bk * 64, n0 = bn * 64;
    #pragma unroll
    for (int i = 0; i < 4; ++i) {
      int jd = i * 256 + tid;
      int r = jd >> 4, c4 = (jd & 15) * 4;
      float4 w4 = *(const float4*)(W + (size_t)(k0 + r) * N + n0 + c4);
      T[c4 + 0][r] = f2bf(w4.x);
      T[c4 + 1][r] = f2bf(w4.y);
      T[c4 + 2][r] = f2bf(w4.z);
      T[c4 + 3][r] = f2bf(w4.w);
    }
    __syncthreads();
    #pragma unroll
    for (int i = 0; i < 4; ++i) {
      int jd = i * 256 + tid;
      int nn = jd >> 4, k4 = (jd & 15) * 4;
      short4v s = *(const short4v*)&T[nn][k4];
      *(short4v*)(Wt + (size_t)(n0 + nn) * K + k0 + k4) = s;
    }
    return;
  }
  __shared__ float sh[4];
  const int row = blockIdx.x;
  const size_t PS = (size_t)2048 * 768;
  size_t ro = (size_t)row * Dd;
  float vv[3];
  #pragma unroll
  for (int i = 0; i < 3; ++i) {
    int c = tid + i * 256;
    float v = bias[c] + res[ro + c];
    #pragma unroll
    for (int s = 0; s < 4; ++s) v += NTL(&pk[s * PS + ro + c]);
    vv[i] = v;
  }
  float m = blk_sum(vv[0] + vv[1] + vv[2], sh) * (1.f / 768.f);
  float var = blk_sum((vv[0]-m)*(vv[0]-m) + (vv[1]-m)*(vv[1]-m) + (vv[2]-m)*(vv[2]-m), sh) * (1.f / 768.f);
  float inv = rsqrtf(var + 1e-6f);
  int bb = row >> 10;
  #pragma unroll
  for (int i = 0; i < 3; ++i) {
    int c = tid + i * 256;
    float o = (vv[i] - m) * inv * sc[c] + bi[c];
    o = film[(size_t)bb * 1536 + c] * o + film[(size_t)bb * 1536 + 768 + c];
    yf[ro + c] = o;
    yb[ro + c] = f2bf(o);
  }
}

// ---------------- plain convT (out_w) and convT2 (ff) ----------------
__global__ __launch_bounds__(256) void convT(const float* __restrict__ W, short* __restrict__ Wt,
                                             int K, int N, int ntile)
{
  __shared__ short T[64][72];
  const int bn = blockIdx.x % ntile, bk = blockIdx.x / ntile;
  const int k0 = bk * 64, n0 = bn * 64, tid = threadIdx.x;
  #pragma unroll
  for (int i = 0; i < 4; ++i) {
    int id = i * 256 + tid;
    int r = id >> 4, c4 = (id & 15) * 4;
    float4 w4 = *(const float4*)(W + (size_t)(k0 + r) * N + n0 + c4);
    T[c4 + 0][r] = f2bf(w4.x);
    T[c4 + 1][r] = f2bf(w4.y);
    T[c4 + 2][r] = f2bf(w4.z);
    T[c4 + 3][r] = f2bf(w4.w);
  }
  __syncthreads();
  #pragma unroll
  for (int i = 0; i < 4; ++i) {
    int id = i * 256 + tid;
    int n = id >> 4, k4 = (id & 15) * 4;
    short4v s = *(const short4v*)&T[n][k4];
    *(short4v*)(Wt + (size_t)(n0 + n) * K + k0 + k4) = s;
  }
}

__global__ __launch_bounds__(256) void convT2(const float* __restrict__ W1, short* __restrict__ D1,
                                              const float* __restrict__ W2, short* __restrict__ D2)
{
  __shared__ short T[64][72];
  const int tid = threadIdx.x;
  const bool second = blockIdx.x >= 576;
  const int id576 = second ? (blockIdx.x - 576) : blockIdx.x;
  const int K = second ? 3072 : 768;
  const int N = second ? 768 : 3072;
  const int ntile = N >> 6;
  const float* W = second ? W2 : W1;
  short* Wt = second ? D2 : D1;
  const int bn = id576 % ntile, bk = id576 / ntile;
  const int k0 = bk * 64, n0 = bn * 64;
  #pragma unroll
  for (int i = 0; i < 4; ++i) {
    int id = i * 256 + tid;
    int r = id >> 4, c4 = (id & 15) * 4;
    float4 w4 = *(const float4*)(W + (size_t)(k0 + r) * N + n0 + c4);
    T[c4 + 0][r] = f2bf(w4.x);
    T[c4 + 1][r] = f2bf(w4.y);
    T[c4 + 2][r] = f2bf(w4.z);
    T[c4 + 3][r] = f2bf(w4.w);
  }
  __syncthreads();
  #pragma unroll
  for (int i = 0; i < 4; ++i) {
    int id = i * 256 + tid;
    int n = id >> 4, k4 = (id & 15) * 4;
    short4v s = *(const short4v*)&T[n][k4];
    *(short4v*)(Wt + (size_t)(n0 + n) * K + k0 + k4) = s;
  }
}

// ---------------- 128x128 bf16 GEMM, BK=32 dbuf, 4 blocks/CU ----------------
template<int ACT>
__global__ __launch_bounds__(256, 4) void gemm_bf(
    const short* __restrict__ A, const short* __restrict__ Bt,
    const float* __restrict__ bias, const float* __restrict__ res,
    float* __restrict__ C, short* __restrict__ Cbf, float* __restrict__ Cpart,
    int M, int N, int K, float scale, int mtiles, int ntiles, int ksplit)
{
  __shared__ short As[2][4096];
  __shared__ short Bs[2][4096];
  const int tid = threadIdx.x, lane = tid & 63, wv = tid >> 6;
  const int l15 = lane & 15, l4 = lane >> 4;

  const int nwg = gridDim.x;
  const int qc = nwg >> 3, rc = nwg & 7;
  const int xcd = blockIdx.x & 7, idx = blockIdx.x >> 3;
  const int wgid = (xcd < rc ? xcd * (qc + 1) : rc * (qc + 1) + (xcd - rc) * qc) + idx;
  const int by = wgid % mtiles;
  const int rest = wgid / mtiles;
  const int bx = rest % ntiles;
  const int sp = rest / ntiles;
  const int kper = K / ksplit;
  const int kbeg = sp * kper;
  const int NT = kper >> 5;

  const int m0 = by * 128, n0 = bx * 128;
  const int wm = (wv >> 1) * 64, wn = (wv & 1) * 64;

  const int srow = lane >> 2, schunk = lane & 3;
  const int scsw = (schunk ^ ((srow >> 1) & 3)) << 3;
  const short* sA = A + (size_t)(m0 + wv * 32 + srow) * K + kbeg + scsw;
  const short* sB = Bt + (size_t)(n0 + wv * 32 + srow) * K + kbeg + scsw;
  const int stBase = wv * 1024;
  const int frsw = (l4 ^ ((l15 >> 1) & 3)) << 3;

  f32x4 acc[4][4];
  const f32x4 zz = {0.f, 0.f, 0.f, 0.f};
  #pragma unroll
  for (int i = 0; i < 4; ++i)
    #pragma unroll
    for (int j = 0; j < 4; ++j) acc[i][j] = zz;

  GL16(sA, &As[0][stBase]);
  GL16(sA + (size_t)16 * K, &As[0][stBase + 512]);
  GL16(sB, &Bs[0][stBase]);
  GL16(sB + (size_t)16 * K, &Bs[0][stBase + 512]);

  int buf = 0;
  for (int t = 0; t < NT; ++t) {
    if (t + 1 < NT) {
      int k0 = (t + 1) << 5;
      GL16(sA + k0, &As[buf ^ 1][stBase]);
      GL16(sA + (size_t)16 * K + k0, &As[buf ^ 1][stBase + 512]);
      GL16(sB + k0, &Bs[buf ^ 1][stBase]);
      GL16(sB + (size_t)16 * K + k0, &Bs[buf ^ 1][stBase + 512]);
      asm volatile("s_waitcnt vmcnt(4)" ::: "memory");
    } else {
      asm volatile("s_waitcnt vmcnt(0)" ::: "memory");
    }
    __builtin_amdgcn_s_barrier();

    short8v af[4], bfv[4];
    #pragma unroll
    for (int mi = 0; mi < 4; ++mi)
      af[mi] = *(const short8v*)&As[buf][(wm + mi * 16 + l15) * 32 + frsw];
    #pragma unroll
    for (int ni = 0; ni < 4; ++ni)
      bfv[ni] = *(const short8v*)&Bs[buf][(wn + ni * 16 + l15) * 32 + frsw];
    __builtin_amdgcn_s_setprio(1);
    #pragma unroll
    for (int mi = 0; mi < 4; ++mi)
      #pragma unroll
      for (int ni = 0; ni < 4; ++ni)
        acc[mi][ni] = __builtin_amdgcn_mfma_f32_16x16x32_bf16(af[mi], bfv[ni], acc[mi][ni], 0, 0, 0);
    __builtin_amdgcn_s_setprio(0);
    if (t + 1 < NT) __builtin_amdgcn_s_barrier();
    buf ^= 1;
  }

  if (Cpart) {
    float* Cp = Cpart + (size_t)sp * M * N;
    #pragma unroll
    for (int mi = 0; mi < 4; ++mi)
      #pragma unroll
      for (int r = 0; r < 4; ++r) {
        int row = m0 + wm + mi * 16 + l4 * 4 + r;
        if (row >= M) continue;
        size_t rb = (size_t)row * N;
        #pragma unroll
        for (int ni = 0; ni < 4; ++ni)
          NTS(acc[mi][ni][r], &Cp[rb + n0 + wn + ni * 16 + l15]);
      }
    return;
  }

  #pragma unroll
  for (int mi = 0; mi < 4; ++mi) {
    #pragma unroll
    for (int r = 0; r < 4; ++r) {
      int row = m0 + wm + mi * 16 + l4 * 4 + r;
      if (row >= M) continue;
      size_t rb = (size_t)row * N;
      #pragma unroll
      for (int ni = 0; ni < 4; ++ni) {
        int col = n0 + wn + ni * 16 + l15;
        float val = (acc[mi][ni][r] + bias[col]) * scale;
        if (ACT == 1) val = fmaxf(val, 0.f);
        if (ACT == 2) val = gelu_f(val);
        if (res) val += res[rb + col];
        if (C)   C[rb + col] = val;
        if (Cbf) Cbf[rb + col] = f2bf(val);
      }
    }
  }
}

// ---------------- 256x256 / 8-wave / BK=64 / 4-phase, 2 barriers/tile (vocab) ----------------
__global__ __launch_bounds__(512, 2) void gemm256(
    const short* __restrict__ A, const short* __restrict__ Bt,
    const float* __restrict__ bias, float* __restrict__ C,
    int M, int N, int K, int mtiles)
{
  __shared__ short As[2][16384];
  __shared__ short Bs[2][16384];
  const int tid = threadIdx.x, lane = tid & 63, wv = tid >> 6;
  const int l15 = lane & 15, l4 = lane >> 4;

  const int nwg = gridDim.x;
  const int qc = nwg >> 3, rc = nwg & 7;
  const int xcd = blockIdx.x & 7, idx = blockIdx.x >> 3;
  const int wgid = (xcd < rc ? xcd * (qc + 1) : rc * (qc + 1) + (xcd - rc) * qc) + idx;
  const int by = wgid % mtiles, bx = wgid / mtiles;
  const int m0 = by * 256, n0 = bx * 256;
  const int wm = (wv >> 2) * 128, wn = (wv & 3) * 64;

  const int srow = lane >> 2, schunk = lane & 3;
  const int scsw = (schunk ^ ((srow >> 1) & 3)) << 3;
  const short* sA = A + (size_t)(m0 + wv * 16 + srow) * K + scsw;
  const short* sB = Bt + (size_t)(n0 + wv * 16 + srow) * K + scsw;
  const int stBase = wv * 512;
  const int frsw = (l4 ^ ((l15 >> 1) & 3)) << 3;

  #define STG_A(b, kk, ko) do { \
    GL16(sA + (ko) + (kk) * 32,                  &As[b][(kk) * 8192 + stBase]); \
    GL16(sA + (size_t)128 * K + (ko) + (kk) * 32, &As[b][(kk) * 8192 + 4096 + stBase]); } while (0)
  #define STG_B(b, kk, ko) do { \
    GL16(sB + (ko) + (kk) * 32,                  &Bs[b][(kk) * 8192 + stBase]); \
    GL16(sB + (size_t)128 * K + (ko) + (kk) * 32, &Bs[b][(kk) * 8192 + 4096 + stBase]); } while (0)
  #define ARD(b, kk, row) (*(const short8v*)&As[b][(kk) * 8192 + (row) * 32 + frsw])
  #define BRD(b, kk, row) (*(const short8v*)&Bs[b][(kk) * 8192 + (row) * 32 + frsw])

  f32x4 acc[8][4];
  const f32x4 zz = {0.f, 0.f, 0.f, 0.f};
  #pragma unroll
  for (int i = 0; i < 8; ++i)
    #pragma unroll
    for (int j = 0; j < 4; ++j) acc[i][j] = zz;

  const int NT = K >> 6;

  STG_A(0, 0, 0); STG_B(0, 0, 0); STG_A(0, 1, 0); STG_B(0, 1, 0);
  asm volatile("s_waitcnt vmcnt(4)" ::: "memory");
  __builtin_amdgcn_s_barrier();

  int buf = 0;
  for (int t = 0; t < NT; ++t) {
    const bool pf = (t + 1 < NT);
    const int k1 = (t + 1) << 6;
    short8v af[4], bfv[4];

    #pragma unroll
    for (int mi = 0; mi < 4; ++mi) af[mi] = ARD(buf, 0, wm + mi * 16 + l15);
    #pragma unroll
    for (int ni = 0; ni < 4; ++ni) bfv[ni] = BRD(buf, 0, wn + ni * 16 + l15);
    if (pf) STG_A(buf ^ 1, 0, k1);
    asm volatile("s_waitcnt lgkmcnt(0)" ::: "memory");
    __builtin_amdgcn_sched_barrier(0);
    __builtin_amdgcn_s_setprio(1);
    #pragma unroll
    for (int mi = 0; mi < 4; ++mi)
      #pragma unroll
      for (int ni = 0; ni < 4; ++ni)
        acc[mi][ni] = __builtin_amdgcn_mfma_f32_16x16x32_bf16(af[mi], bfv[ni], acc[mi][ni], 0, 0, 0);
    __builtin_amdgcn_s_setprio(0);

    #pragma unroll
    for (int mi = 0; mi < 4; ++mi) af[mi] = ARD(buf, 0, wm + 64 + mi * 16 + l15);
    if (pf) STG_B(buf ^ 1, 0, k1);
    asm volatile("s_waitcnt lgkmcnt(0)" ::: "memory");
    __builtin_amdgcn_sched_barrier(0);
    __builtin_amdgcn_s_setprio(1);
    #pragma unroll
    for (int mi = 0; mi < 4; ++mi)
      #pragma unroll
      for (int ni = 0; ni < 4; ++ni)
        acc[4 + mi][ni] = __builtin_amdgcn_mfma_f32_16x16x32_bf16(af[mi], bfv[ni], acc[4 + mi][ni], 0, 0, 0);
    __builtin_amdgcn_s_setprio(0);
    if (pf) asm volatile("s_waitcnt vmcnt(4)" ::: "memory");
    else    asm volatile("s_waitcnt vmcnt(0)" ::: "memory");
    __builtin_amdgcn_s_barrier();

    #pragma unroll
    for (int mi = 0; mi < 4; ++mi) af[mi] = ARD(buf, 1, wm + mi * 16 + l15);
    #pragma unroll
    for (int ni = 0; ni < 4; ++ni) bfv[ni] = BRD(buf, 1, wn + ni * 16 + l15);
    if (pf) STG_A(buf ^ 1, 1, k1);
    asm volatile("s_waitcnt lgkmcnt(0)" ::: "memory");
    __builtin_amdgcn_sched_barrier(0);
    __builtin_amdgcn_s_setprio(1);
    #pragma unroll
    for (int mi = 0; mi < 4; ++mi)
      #pragma unroll
      for (int ni = 0; ni < 4; ++ni)
        acc[mi][ni] = __builtin_amdgcn_mfma_f32_16x16x32_bf16(af[mi], bfv[ni], acc[mi][ni], 0, 0, 0);
    __builtin_amdgcn_s_setprio(0);

    #pragma unroll
    for (int mi = 0; mi < 4; ++mi) af[mi] = ARD(buf, 1, wm + 64 + mi * 16 + l15);
    if (pf) STG_B(buf ^ 1, 1, k1);
    asm volatile("s_waitcnt lgkmcnt(0)" ::: "memory");
    __builtin_amdgcn_sched_barrier(0);
    __builtin_amdgcn_s_setprio(1);
    #pragma unroll
    for (int mi = 0; mi < 4; ++mi)
      #pragma unroll
      for (int ni = 0; ni < 4; ++ni)
        acc[4 + mi][ni] = __builtin_amdgcn_mfma_f32_16x16x32_bf16(af[mi], bfv[ni], acc[4 + mi][ni], 0, 0, 0);
    __builtin_amdgcn_s_setprio(0);
    if (pf) {
      asm volatile("s_waitcnt vmcnt(4)" ::: "memory");
      __builtin_amdgcn_s_barrier();
    }
    buf ^= 1;
  }

  #pragma unroll
  for (int mi = 0; mi < 8; ++mi) {
    #pragma unroll
    for (int r = 0; r < 4; ++r) {
      int row = m0 + wm + mi * 16 + l4 * 4 + r;
      size_t rb = (size_t)row * N;
      #pragma unroll
      for (int ni = 0; ni < 4; ++ni) {
        int col = n0 + wn + ni * 16 + l15;
        NTS(acc[mi][ni][r] + bias[col], &C[rb + col]);
      }
    }
  }
  #undef STG_A
  #undef STG_B
  #undef ARD
  #undef BRD
}

// ---------------- flash attention, 4-chunk KV-split, q assembled in-kernel ----------------
__global__ __launch_bounds__(256) void attn_kernel(
    const short* __restrict__ kvq, const float* __restrict__ bq,
    float* __restrict__ Op0, float* __restrict__ Op1,
    float* __restrict__ Op2, float* __restrict__ Op3, float* __restrict__ ml)
{
  __shared__ short Kls[64][104];
  __shared__ short Vt[96][72];
  __shared__ short Pls[4][16][72];

  const int tid = threadIdx.x, lane = tid & 63, w = tid >> 6;
  const int l15 = lane & 15, l4 = lane >> 4;
  const int chunk = blockIdx.x >> 8;
  const int inner = blockIdx.x & 255;
  const int qt = inner & 15;
  const int bh = inner >> 4;
  const int h = bh & 7, b = bh >> 3;
  const int qb = qt * 64;
  const int qw = qb + w * 16;
  const float qsc = 0.1020620726159658f;   // 1/sqrt(96)

  short8v qf[3];
  {
    const short* p1 = kvq + ((size_t)b * KVr + 1 + qw + l15) * 2304 + h * HDh + l4 * 8;
    const short* p2 = p1 + (size_t)Ss * 2304;
    #pragma unroll
    for (int kk = 0; kk < 3; ++kk) {
      short8v a8 = *(const short8v*)(p1 + kk * 32);
      short8v b8 = *(const short8v*)(p2 + kk * 32);
      short8v tq;
      #pragma unroll
      for (int j = 0; j < 8; ++j)
        tq[j] = f2bf((bf2f(a8[j]) + bf2f(b8[j]) + bq[h * HDh + kk * 32 + l4 * 8 + j]) * qsc);
      qf[kk] = tq;
    }
  }

  const f32x4 zz = {0.f, 0.f, 0.f, 0.f};
  f32x4 Oa[6];
  #pragma unroll
  for (int fn = 0; fn < 6; ++fn) Oa[fn] = zz;
  float mrow[4], lrow[4];
  #pragma unroll
  for (int r = 0; r < 4; ++r) { mrow[r] = -3.0e38f; lrow[r] = 0.f; }

  const size_t kvbase = (size_t)b * KVr;

  for (int t = chunk; t < 33; t += 4) {
    int k0 = t * 64;
    bool l2r_vis = (k0 <= Ss) && (k0 - 1 <= qb + 63);
    int rmaxk = (k0 + 63 > 2 * Ss) ? 2 * Ss : (k0 + 63);
    bool r2l_vis = (k0 + 63 >= Ss + 1) && (rmaxk - (Ss + 1) >= qb);
    if (!(t == 0 || l2r_vis || r2l_vis)) continue;

    __syncthreads();
    #pragma unroll
    for (int i = 0; i < 3; ++i) {
      int id = i * 256 + tid;
      int row = id / 12, cc = (id % 12) * 8;
      int key = k0 + row;
      if (key > 2 * Ss) key = 2 * Ss;
      const short* kp = kvq + (kvbase + key) * 2304 + 768 + h * HDh + cc;
      short8v k8 = *(const short8v*)kp;
      *(short8v*)&Kls[row][cc] = k8;
      short8v v8 = *(const short8v*)(kp + 768);
      #pragma unroll
      for (int j = 0; j < 8; ++j) Vt[cc + j][row] = v8[j];
    }
    __syncthreads();

    f32x4 sc[4];
    #pragma unroll
    for (int nt = 0; nt < 4; ++nt) {
      f32x4 d = zz;
      #pragma unroll
      for (int kk = 0; kk < 3; ++kk) {
        short8v kf = *(const short8v*)&Kls[nt * 16 + l15][kk * 32 + l4 * 8];
        d = __builtin_amdgcn_mfma_f32_16x16x32_bf16(qf[kk], kf, d, 0, 0, 0);
      }
      sc[nt] = d;
    }
    float tmax[4] = {-3.0e38f, -3.0e38f, -3.0e38f, -3.0e38f};
    #pragma unroll
    for (int nt = 0; nt < 4; ++nt)
      #pragma unroll
      for (int r = 0; r < 4; ++r) {
        int qg = qw + l4 * 4 + r;
        int j = k0 + nt * 16 + l15;
        bool vis = (j == 0) ||
                   (j >= 1 && j <= Ss && (j - 1) <= qg) ||
                   (j >= Ss + 1 && j <= 2 * Ss && (j - (Ss + 1)) >= qg);
        if (!vis) sc[nt][r] = -3.0e38f;
        tmax[r] = fmaxf(tmax[r], sc[nt][r]);
      }
    #pragma unroll
    for (int r = 0; r < 4; ++r) {
      #pragma unroll
      for (int off = 8; off >= 1; off >>= 1) tmax[r] = fmaxf(tmax[r], __shfl_xor(tmax[r], off));
    }
    float scl[4];
    #pragma unroll
    for (int r = 0; r < 4; ++r) {
      float mnew = fmaxf(mrow[r], tmax[r]);
      scl[r] = __expf(mrow[r] - mnew);
      mrow[r] = mnew;
    }
    #pragma unroll
    for (int fn = 0; fn < 6; ++fn)
      #pragma unroll
      for (int r = 0; r < 4; ++r) Oa[fn][r] *= scl[r];
    float lad[4] = {0.f, 0.f, 0.f, 0.f};
    #pragma unroll
    for (int nt = 0; nt < 4; ++nt)
      #pragma unroll
      for (int r = 0; r < 4; ++r) {
        float p = __expf(sc[nt][r] - mrow[r]);
        lad[r] += p;
        Pls[w][l4 * 4 + r][nt * 16 + l15] = f2bf(p);
      }
    #pragma unroll
    for (int r = 0; r < 4; ++r) {
      #pragma unroll
      for (int off = 8; off >= 1; off >>= 1) lad[r] += __shfl_xor(lad[r], off);
      lrow[r] = lrow[r] * scl[r] + lad[r];
    }
    __syncthreads();

    short8v pf[2];
    #pragma unroll
    for (int kk = 0; kk < 2; ++kk) pf[kk] = *(const short8v*)&Pls[w][l15][kk * 32 + l4 * 8];
    #pragma unroll
    for (int fn = 0; fn < 6; ++fn) {
      #pragma unroll
      for (int kk = 0; kk < 2; ++kk) {
        short8v vf = *(const short8v*)&Vt[fn * 16 + l15][kk * 32 + l4 * 8];
        Oa[fn] = __builtin_amdgcn_mfma_f32_16x16x32_bf16(pf[kk], vf, Oa[fn], 0, 0, 0);
      }
    }
  }

  float* Op = (chunk == 0) ? Op0 : (chunk == 1) ? Op1 : (chunk == 2) ? Op2 : Op3;
  #pragma unroll
  for (int fn = 0; fn < 6; ++fn)
    #pragma unroll
    for (int r = 0; r < 4; ++r) {
      int row = qw + l4 * 4 + r;
      int col = h * HDh + fn * 16 + l15;
      NTS(Oa[fn][r], &Op[((size_t)(b * Ss + row)) * Dd + col]);
    }
  if (l15 == 0) {
    #pragma unroll
    for (int r = 0; r < 4; ++r) {
      int row = qw + l4 * 4 + r;
      size_t ix = (size_t)chunk * 32768 + (((size_t)(b * 8 + h) * 1024 + row) * 2);
      ml[ix] = mrow[r];
      ml[ix + 1] = lrow[r];
    }
  }
}

// online-softmax merge of the 4 KV chunks -> attn_bf
__global__ __launch_bounds__(256) void attn_merge(
    const float* __restrict__ Op0, const float* __restrict__ Op1,
    const float* __restrict__ Op2, const float* __restrict__ Op3,
    const float* __restrict__ ml, short* __restrict__ o)
{
  const int row = blockIdx.x, tid = threadIdx.x;
  const int b = row >> 10, s = row & 1023;
  size_t ro = (size_t)row * Dd;
  #pragma unroll
  for (int i = 0; i < 3; ++i) {
    int c = tid + i * 256;
    int h = c / HDh;
    size_t ix = ((size_t)(b * 8 + h) * 1024 + s) * 2;
    float m0 = ml[ix], l0 = ml[ix + 1];
    float m1 = ml[32768 + ix], l1 = ml[32768 + ix + 1];
    float m2 = ml[65536 + ix], l2 = ml[65536 + ix + 1];
    float m3 = ml[98304 + ix], l3 = ml[98304 + ix + 1];
    float mm = fmaxf(fmaxf(m0, m1), fmaxf(m2, m3));
    float s0 = __expf(m0 - mm), s1 = __expf(m1 - mm);
    float s2 = __expf(m2 - mm), s3 = __expf(m3 - mm);
    float denom = s0 * l0 + s1 * l1 + s2 * l2 + s3 * l3;
    float val = s0 * NTL(&Op0[ro + c]) + s1 * NTL(&Op1[ro + c])
              + s2 * NTL(&Op2[ro + c]) + s3 * NTL(&Op3[ro + c]);
    o[ro + c] = f2bf(val / denom);
  }
}

// ---------------- launch helpers ----------------
static void gemm_launch(int act, const short* A, const short* Bt, const float* bias,
                        const float* res, float* C, short* Cbf, float* Cpart,
                        int M, int N, int K, float scale, int ksplit, hipStream_t s)
{
  int mt = (M + 127) >> 7, nt = N >> 7;
  dim3 grid(mt * nt * ksplit), blk(256);
  if (act == 1)      gemm_bf<1><<<grid, blk, 0, s>>>(A, Bt, bias, res, C, Cbf, Cpart, M, N, K, scale, mt, nt, ksplit);
  else if (act == 2) gemm_bf<2><<<grid, blk, 0, s>>>(A, Bt, bias, res, C, Cbf, Cpart, M, N, K, scale, mt, nt, ksplit);
  else               gemm_bf<0><<<grid, blk, 0, s>>>(A, Bt, bias, res, C, Cbf, Cpart, M, N, K, scale, mt, nt, ksplit);
}

extern "C" void kernel_launch(void* const* d_in, const int* in_sizes, int n_in,
                              void* d_out, int out_size, void* d_ws, size_t ws_size,
                              hipStream_t stream)
{
  (void)in_sizes; (void)n_in; (void)out_size; (void)ws_size;
  const float* l2r      = (const float*)d_in[0];
  const float* r2l      = (const float*)d_in[1];
  const float* temb     = (const float*)d_in[2];
  const float* ln_l2r_s = (const float*)d_in[3];
  const float* ln_l2r_b = (const float*)d_in[4];
  const float* ln_r2l_s = (const float*)d_in[5];
  const float* ln_r2l_b = (const float*)d_in[6];
  const float* Wq = (const float*)d_in[7];
  const float* bq = (const float*)d_in[8];
  const float* Wk = (const float*)d_in[9];
  const float* bk = (const float*)d_in[10];
  const float* Wv = (const float*)d_in[11];
  const float* bv = (const float*)d_in[12];
  const float* Wo = (const float*)d_in[13];
  const float* bo = (const float*)d_in[14];
  const float* ff_ln_s = (const float*)d_in[15];
  const float* ff_ln_b = (const float*)d_in[16];
  const float* ff_w1 = (const float*)d_in[17];
  const float* ff_b1 = (const float*)d_in[18];
  const float* ff_w2 = (const float*)d_in[19];
  const float* ff_b2 = (const float*)d_in[20];
  const float* tm_w1 = (const float*)d_in[21];
  const float* tm_b1 = (const float*)d_in[22];
  const float* tm_w2 = (const float*)d_in[23];
  const float* tm_b2 = (const float*)d_in[24];
  const float* film_w = (const float*)d_in[25];
  const float* film_b = (const float*)d_in[26];
  const float* r_w1 = (const float*)d_in[27];
  const float* r_b1 = (const float*)d_in[28];
  const float* r_w2 = (const float*)d_in[29];
  const float* r_b2 = (const float*)d_in[30];
  const float* r_ln_s = (const float*)d_in[31];
  const float* r_ln_b = (const float*)d_in[32];
  const float* out_w = (const float*)d_in[33];
  const float* out_b = (const float*)d_in[34];

  uint8_t* base = (uint8_t*)d_ws;
  // layout identical to round 13 (liveness-verified)
  short* alle_bf = (short*)(base + 3145728);
  short* kvq     = (short*)(base + 9440256);    // ends 28,323,840
  short* attn_bf = (short*)(base + 12585984);
  float* inputs  = (float*)(base + 28323840);
  float* xbuf    = (float*)(base + 34615296);
  short* xn_bf   = (short*)(base + 40906752);
  short* big_bf  = (short*)(base + 44052480);
  float* x2f     = (float*)(base + 56635392);
  short* x2bf    = (short*)(base + 62926848);
  float* x3f     = (float*)(base + 66072576);
  short* x3bf    = (short*)(base + 72364032);
  short* x4bf    = (short*)(base + 75509760);
  short* wslot   = (short*)(base + 78655488);
  uint8_t* sm    = base + 83374080;
  float* f0    = (float*)(sm + 0);
  float* f1    = (float*)(sm + 12288);
  float* kvbia = (float*)(sm + 24576);
  short* w2slot = (short*)inputs;
  float* part2a = (float*)(base + 44052480);
  float* part2b = (float*)(base + 44052480 + 1572864);
  float* part2c = (float*)(base + 44052480 + 3145728);
  float* Op0 = (float*)(base + 3145728);
  float* Op1 = xbuf;
  float* Op2 = (float*)(base + 44052480);
  float* Op3 = (float*)(base + 50343936);
  float* mlb = (float*)(base + 56635392);
  float* wopart = (float*)(base + 44052480);
  float* partK = (float*)(base + 0);
  short* outwT = (short*)(base + 0);

  dim3 blk(256);

  // 1-3. t-path: thin1 -> thin1p(gelu+tm_w2) -> film1p (film2 folded into prep_conv)
  thin1<<<dim3(12 * 64), blk, 0, stream>>>(temb, tm_w1, part2a, 768, 3072, 12, 64);
  thin1p<<<dim3(12 * 64), blk, 0, stream>>>(part2a, tm_b1, tm_w2, part2b);
  film1p<<<dim3(12 * 64), blk, 0, stream>>>(part2b, tm_b2, film_w, part2c);

  // 4. prep + QKVO weight convert + bias concat + film2
  prep_conv<<<dim3(2639), blk, 0, stream>>>(l2r, r2l, temb, ln_l2r_s, ln_l2r_b, ln_r2l_s, ln_r2l_b,
                                            inputs, alle_bf, Wq, Wk, Wv, Wo, bk, bv, wslot, kvbia,
                                            part2c, film_b, f0, f1);

  // 5. fused QKV projection: E[4098,768] @ [Wq|Wk|Wv] -> kvq[4098,2304] bf16
  gemm_launch(0, alle_bf, wslot, kvbia, nullptr, nullptr, kvq, nullptr, 4098, 2304, 768, 1.f, 1, stream);

  // 6-7. attention (q assembled in-kernel), 4 KV chunks + merge
  attn_kernel<<<dim3(1024), blk, 0, stream>>>(kvq, bq, Op0, Op1, Op2, Op3, mlb);
  attn_merge<<<dim3(2048), blk, 0, stream>>>(Op0, Op1, Op2, Op3, mlb, attn_bf);

  // 8-9. Wo projection split-K(2) + fused combine/residual/LN
  gemm_launch(0, attn_bf, wslot + (size_t)3 * 768 * 768, bo, nullptr, nullptr, nullptr, wopart, 2048, 768, 768, 1.f, 2, stream);
  ln_comb2<<<dim3(2048), blk, 0, stream>>>(wopart, bo, inputs, ff_ln_s, ff_ln_b, xbuf, xn_bf);

  // 10-12. ff block
  convT2<<<dim3(1152), blk, 0, stream>>>(ff_w1, wslot, ff_w2, w2slot);
  gemm_launch(1, xn_bf, wslot, ff_b1, nullptr, nullptr, big_bf, nullptr, 2048, 3072, 768, 1.f, 1, stream);
  gemm_launch(0, big_bf, w2slot, nullptr, nullptr, nullptr, nullptr, partK, 2048, 768, 3072, 1.f, 4, stream);

  // 13. combine(ff) + convT2(r0) merged
  comb_convT2<<<dim3(3200), blk, 0, stream>>>(partK, ff_b2, xbuf, x2f, x2bf,
                                              r_w1, wslot, r_w2, w2slot);

  // 14-15. residual block 0 GEMMs
  gemm_launch(2, x2bf, wslot, r_b1, nullptr, nullptr, big_bf, nullptr, 2048, 3072, 768, 1.f, 1, stream);
  gemm_launch(0, big_bf, w2slot, nullptr, nullptr, nullptr, nullptr, partK, 2048, 768, 3072, 1.f, 4, stream);

  // 16. ln_comb(r0) + convT2(r1) merged
  lncomb_convT2<<<dim3(3200), blk, 0, stream>>>(partK, r_b2, x2f, r_ln_s, r_ln_b, f0, x3f, x3bf,
                                                r_w1 + (size_t)768 * 3072, wslot,
                                                r_w2 + (size_t)3072 * 768, w2slot);

  // 17-18. residual block 1 GEMMs
  gemm_launch(2, x3bf, wslot, r_b1 + 3072, nullptr, nullptr, big_bf, nullptr, 2048, 3072, 768, 1.f, 1, stream);
  gemm_launch(0, big_bf, w2slot, nullptr, nullptr, nullptr, nullptr, partK, 2048, 768, 3072, 1.f, 4, stream);

  // 19. ln_comb(r1)
  ln_comb<<<dim3(2048), blk, 0, stream>>>(partK, r_b2 + 768, x3f, r_ln_s + 768, r_ln_b + 768, f1, nullptr, x4bf);

  // 20-21. vocab projection
  convT<<<dim3(6000), blk, 0, stream>>>(out_w, outwT, 768, 32000, 500);
  gemm256<<<dim3(8 * 125), dim3(512), 0, stream>>>(x4bf, outwT, out_b, (float*)d_out,
                                                   2048, 32000, 768, 8);
}